// Round 1
// baseline (441.231 us; speedup 1.0000x reference)
//
#include <hip/hip_runtime.h>
#include <hip/hip_bf16.h>
#include <math.h>

#define HID 4096
#define NH 32
#define HD 128
#define EDGE 24
#define KW 12
#define PEW 13
#define VT 576
#define OFF 5
#define NB 2
#define SLEN 1024
#define NQ 448
#define QCHUNK 28
#define NCHUNK 16

typedef short bf16x8 __attribute__((ext_vector_type(8)));
typedef float f32x4 __attribute__((ext_vector_type(4)));
typedef unsigned int u32;

static __device__ __forceinline__ unsigned short f2bf(float f) {
  union { float f; u32 u; } v; v.f = f;
  u32 u = v.u;
  return (unsigned short)((u + 0x7fffu + ((u >> 16) & 1u)) >> 16);
}

static __device__ __forceinline__ float dot4(float4 a, float4 b) {
  return a.x * b.x + a.y * b.y + a.z * b.z + a.w * b.w;
}

static __device__ __forceinline__ void load_lds16(const void* g, void* l) {
  __builtin_amdgcn_global_load_lds((const __attribute__((address_space(1))) u32*)g,
                                   (__attribute__((address_space(3))) u32*)l, 16, 0, 0);
}

// ---------------- Kernel A: f32 -> bf16 convert (W_in) ----------------
__global__ __launch_bounds__(256) void k_cvt(const float* __restrict__ in,
                                             unsigned short* __restrict__ out, int n4) {
  int i = blockIdx.x * 256 + threadIdx.x;
  if (i < n4) {
    float4 v = ((const float4*)in)[i];
    ushort4 o;
    o.x = f2bf(v.x); o.y = f2bf(v.y); o.z = f2bf(v.z); o.w = f2bf(v.w);
    ((ushort4*)out)[i] = o;
  }
}

// ---------------- Kernel B: scores + row softmax + partial colsums ----------------
// grid = NB*NH*NCHUNK blocks of 256. Each block: QCHUNK q-rows of one (b,h),
// each thread owns 4 k-columns (k = tid + j*256). Scores stay in registers (f32).
__global__ __launch_bounds__(256) void k_scores(const float* __restrict__ hid,
                                                float* __restrict__ part) {
  int bid = blockIdx.x;
  int chunk = bid % NCHUNK;
  int bh = bid / NCHUNK;
  int b = bh / NH, h = bh % NH;
  int t = threadIdx.x;
  int wv = t >> 6, ln = t & 63;

  __shared__ float qt[QCHUNK][HD];
  __shared__ float redm[QCHUNK][4];
  __shared__ float redz[QCHUNK][4];

  const float* base = hid + (size_t)b * SLEN * HID + (size_t)h * HD;

  // load q tile (rows remapped to skip masked region)
  for (int idx = t; idx < QCHUNK * (HD / 4); idx += 256) {
    int qi = idx >> 5;          // /32 float4-per-row
    int c4 = idx & 31;
    int q = chunk * QCHUNK + qi;
    q = (q < OFF) ? q : q + VT;
    float4 v = *(const float4*)(base + (size_t)q * HID + c4 * 4);
    *(float4*)&qt[qi][c4 * 4] = v;
  }
  __syncthreads();

  float sc[QCHUNK][4];
#pragma unroll
  for (int q = 0; q < QCHUNK; ++q)
#pragma unroll
    for (int j = 0; j < 4; ++j) sc[q][j] = 0.f;

  const float* kr0 = base + (size_t)(t +   0) * HID;
  const float* kr1 = base + (size_t)(t + 256) * HID;
  const float* kr2 = base + (size_t)(t + 512) * HID;
  const float* kr3 = base + (size_t)(t + 768) * HID;

  for (int c = 0; c < 32; ++c) {
    float4 kv0 = *(const float4*)(kr0 + c * 4);
    float4 kv1 = *(const float4*)(kr1 + c * 4);
    float4 kv2 = *(const float4*)(kr2 + c * 4);
    float4 kv3 = *(const float4*)(kr3 + c * 4);
#pragma unroll
    for (int q = 0; q < QCHUNK; ++q) {
      float4 qv = *(const float4*)&qt[q][c * 4];
      sc[q][0] += dot4(qv, kv0);
      sc[q][1] += dot4(qv, kv1);
      sc[q][2] += dot4(qv, kv2);
      sc[q][3] += dot4(qv, kv3);
    }
  }

  const float scale = 0.088388347648318447f;  // 1/sqrt(128)
#pragma unroll
  for (int q = 0; q < QCHUNK; ++q)
#pragma unroll
    for (int j = 0; j < 4; ++j) sc[q][j] *= scale;

  // per-q block max
#pragma unroll
  for (int q = 0; q < QCHUNK; ++q) {
    float m = fmaxf(fmaxf(sc[q][0], sc[q][1]), fmaxf(sc[q][2], sc[q][3]));
#pragma unroll
    for (int o = 32; o > 0; o >>= 1) m = fmaxf(m, __shfl_xor(m, o));
    if (ln == 0) redm[q][wv] = m;
  }
  __syncthreads();
  // per-q block sum of exp
#pragma unroll
  for (int q = 0; q < QCHUNK; ++q) {
    float M = fmaxf(fmaxf(redm[q][0], redm[q][1]), fmaxf(redm[q][2], redm[q][3]));
    float z = __expf(sc[q][0] - M) + __expf(sc[q][1] - M) +
              __expf(sc[q][2] - M) + __expf(sc[q][3] - M);
#pragma unroll
    for (int o = 32; o > 0; o >>= 1) z += __shfl_xor(z, o);
    if (ln == 0) redz[q][wv] = z;
  }
  __syncthreads();

  float cs0 = 0.f, cs1 = 0.f, cs2 = 0.f, cs3 = 0.f;
#pragma unroll
  for (int q = 0; q < QCHUNK; ++q) {
    float M = fmaxf(fmaxf(redm[q][0], redm[q][1]), fmaxf(redm[q][2], redm[q][3]));
    float invZ = 1.f / (redz[q][0] + redz[q][1] + redz[q][2] + redz[q][3]);
    cs0 += __expf(sc[q][0] - M) * invZ;
    cs1 += __expf(sc[q][1] - M) * invZ;
    cs2 += __expf(sc[q][2] - M) * invZ;
    cs3 += __expf(sc[q][3] - M) * invZ;
  }

  float* pdst = part + ((size_t)bh * NCHUNK + chunk) * VT;
  int k0 = t;
  if (k0 >= OFF && k0 < OFF + VT) pdst[k0 - OFF] = cs0;
  int k1 = t + 256;
  if (k1 < OFF + VT) pdst[k1 - OFF] = cs1;
  int k2 = t + 512;
  if (k2 < OFF + VT) pdst[k2 - OFF] = cs2;
  // k3 = t + 768 >= 581 always: never in range
  (void)cs3;
}

// ---------------- Kernel C: per-head softmax / pool / argmax / w ----------------
__global__ __launch_bounds__(256) void k_head(const float* __restrict__ part,
                                              float* __restrict__ params) {
  int bh = blockIdx.x;
  int t = threadIdx.x;
  __shared__ float ia[VT];
  __shared__ float sfe[VT];   // unnormalized exp
  __shared__ float rbuf[256];
  __shared__ int ribuf[256];

  for (int i = t; i < VT; i += 256) {
    float s = 0.f;
    const float* p = part + (size_t)bh * NCHUNK * VT + i;
    for (int c = 0; c < NCHUNK; ++c) s += p[(size_t)c * VT];
    ia[i] = s;
  }
  __syncthreads();

  // block max over 576
  float lm = -1e30f;
  for (int i = t; i < VT; i += 256) lm = fmaxf(lm, ia[i]);
  rbuf[t] = lm;
  __syncthreads();
  for (int s = 128; s > 0; s >>= 1) {
    if (t < s) rbuf[t] = fmaxf(rbuf[t], rbuf[t + s]);
    __syncthreads();
  }
  float M = rbuf[0];
  __syncthreads();

  // exp + sum
  float lz = 0.f;
  for (int i = t; i < VT; i += 256) {
    float e = __expf(ia[i] - M);
    sfe[i] = e;
    lz += e;
  }
  rbuf[t] = lz;
  __syncthreads();
  for (int s = 128; s > 0; s >>= 1) {
    if (t < s) rbuf[t] += rbuf[t + s];
    __syncthreads();
  }
  float invZ = 1.f / rbuf[0];
  __syncthreads();

  // pooled window sums + argmax (tie -> lowest index, matching jnp.argmax)
  float pv = -1e30f;
  int pidx = 0x7fffffff;
  if (t < PEW * PEW) {
    int r = t / PEW, c = t % PEW;
    float s = 0.f;
    for (int i = 0; i < KW; ++i)
      for (int j = 0; j < KW; ++j) s += ia[(r + i) * EDGE + (c + j)];
    pv = s;
    pidx = t;
  }
  rbuf[t] = pv;
  ribuf[t] = pidx;
  __syncthreads();
  for (int s = 128; s > 0; s >>= 1) {
    if (t < s) {
      float ov = rbuf[t + s];
      int oi = ribuf[t + s];
      if (ov > rbuf[t] || (ov == rbuf[t] && oi < ribuf[t])) {
        rbuf[t] = ov;
        ribuf[t] = oi;
      }
    }
    __syncthreads();
  }
  int idx = ribuf[0];
  int r0 = idx / PEW, c0 = idx % PEW;
  __syncthreads();

  // w = sum of softmax window
  float lw = 0.f;
  if (t < KW * KW) {
    int i = t / KW, j = t % KW;
    lw = sfe[(r0 + i) * EDGE + (c0 + j)];
  }
  rbuf[t] = lw;
  __syncthreads();
  for (int s = 128; s > 0; s >>= 1) {
    if (t < s) rbuf[t] += rbuf[t + s];
    __syncthreads();
  }
  if (t == 0) {
    params[bh * 4 + 0] = rbuf[0] * invZ;
    ((int*)params)[bh * 4 + 1] = r0;
    ((int*)params)[bh * 4 + 2] = c0;
  }
}

// ---------------- Kernel D1: copy non-image rows -> bf16 hs ----------------
__global__ __launch_bounds__(256) void k_copy(const float* __restrict__ hid,
                                              unsigned short* __restrict__ hs) {
  int i = blockIdx.x * 256 + threadIdx.x;  // over NB*448*(HID/4)
  int c4 = i & (HID / 4 - 1);
  int r = (i >> 10) % 448;
  int b = i / (448 * (HID / 4));
  int s = (r < OFF) ? r : r + VT;
  size_t off = ((size_t)(b * SLEN + s)) * HID + c4 * 4;
  float4 v = *(const float4*)(hid + off);
  ushort4 o;
  o.x = f2bf(v.x); o.y = f2bf(v.y); o.z = f2bf(v.z); o.w = f2bf(v.w);
  *(ushort4*)(hs + off) = o;
}

// ---------------- Kernel D2: per-head window up-projection -> bf16 hs ----------------
// grid = NB*NH*4; block handles 36 of the 144 (i,j) cells for one (b,h).
__global__ __launch_bounds__(256) void k_img(const float* __restrict__ hid,
                                             const float* __restrict__ Wup,
                                             const float* __restrict__ params,
                                             unsigned short* __restrict__ hs) {
  int bid = blockIdx.x;
  int g = bid & 3;
  int bh = bid >> 2;
  int b = bh / NH, h = bh % NH;
  float w = params[bh * 4];
  int r0 = ((const int*)params)[bh * 4 + 1];
  int c0 = ((const int*)params)[bh * 4 + 2];
  int t = threadIdx.x;

  __shared__ float win[36][HD];
  for (int idx = t; idx < 36 * (HD / 4); idx += 256) {
    int cell = idx >> 5;
    int c4 = idx & 31;
    int cc = g * 36 + cell;
    int i = cc / 12, j = cc % 12;
    int s = OFF + (r0 + i) * EDGE + (c0 + j);
    *(float4*)&win[cell][c4 * 4] =
        *(const float4*)(hid + ((size_t)(b * SLEN + s)) * HID + h * HD + c4 * 4);
  }
  __syncthreads();

  float acc0[36], acc1[36];
#pragma unroll
  for (int cell = 0; cell < 36; ++cell) { acc0[cell] = 0.f; acc1[cell] = 0.f; }

  int e0 = t, e1 = t + 256;
  const float* w0 = Wup + (size_t)e0 * HD;
  const float* w1 = Wup + (size_t)e1 * HD;
  for (int c = 0; c < 32; ++c) {
    float4 u0 = *(const float4*)(w0 + c * 4);
    float4 u1 = *(const float4*)(w1 + c * 4);
#pragma unroll
    for (int cell = 0; cell < 36; ++cell) {
      float4 qv = *(const float4*)&win[cell][c * 4];
      acc0[cell] += dot4(qv, u0);
      acc1[cell] += dot4(qv, u1);
    }
  }

  int si0 = e0 >> 8, sj0 = (e0 >> 7) & 1, d0 = e0 & 127;
  int si1 = e1 >> 8, sj1 = (e1 >> 7) & 1, d1 = e1 & 127;
#pragma unroll
  for (int cell = 0; cell < 36; ++cell) {
    int cc = g * 36 + cell;
    int i = cc / 12, j = cc % 12;
    {
      int srow = OFF + (2 * i + si0) * EDGE + (2 * j + sj0);
      hs[((size_t)(b * SLEN + srow)) * HID + h * HD + d0] = f2bf(acc0[cell] * w);
    }
    {
      int srow = OFF + (2 * i + si1) * EDGE + (2 * j + sj1);
      hs[((size_t)(b * SLEN + srow)) * HID + h * HD + d1] = f2bf(acc1[cell] * w);
    }
  }
}

// ---------------- Kernel E: bf16 MFMA GEMM, silu + residual epilogue ----------------
// C[m,e] = resid[m,e] + silu( sum_d A[m,d] * W[e,d] ),  M=2048, N=K=4096
__global__ __launch_bounds__(256) void k_gemm(const unsigned short* __restrict__ A,
                                              const unsigned short* __restrict__ Bm,
                                              const float* __restrict__ resid,
                                              float* __restrict__ out) {
  int bid = blockIdx.x;
  int bm0 = (bid & 15) << 7;
  int bn0 = (bid >> 4) << 7;
  int t = threadIdx.x;
  int ln = t & 63, wv = t >> 6;
  int wr = wv >> 1, wc = wv & 1;

  __shared__ unsigned short lA[128 * 64];
  __shared__ unsigned short lB[128 * 64];

  f32x4 acc[4][4];
#pragma unroll
  for (int mi = 0; mi < 4; ++mi)
#pragma unroll
    for (int ni = 0; ni < 4; ++ni) acc[mi][ni] = (f32x4){0.f, 0.f, 0.f, 0.f};

  const unsigned short* aptr = A + (size_t)(bm0 + (t >> 3)) * HID + (t & 7) * 8;
  const unsigned short* bptr = Bm + (size_t)(bn0 + (t >> 3)) * HID + (t & 7) * 8;
  unsigned short* la = &lA[t * 8];
  unsigned short* lb = &lB[t * 8];

  int arow_a = (wr * 64 + (ln & 15)) * 64 + (ln >> 4) * 8;
  int arow_b = (wc * 64 + (ln & 15)) * 64 + (ln >> 4) * 8;

  for (int k0 = 0; k0 < HID; k0 += 64) {
#pragma unroll
    for (int i = 0; i < 4; ++i)
      load_lds16(aptr + (size_t)i * 32 * HID + k0, la + i * 2048);
#pragma unroll
    for (int i = 0; i < 4; ++i)
      load_lds16(bptr + (size_t)i * 32 * HID + k0, lb + i * 2048);
    __syncthreads();
#pragma unroll
    for (int ks = 0; ks < 2; ++ks) {
      bf16x8 aF[4], bF[4];
#pragma unroll
      for (int mi = 0; mi < 4; ++mi)
        aF[mi] = *(const bf16x8*)&lA[arow_a + mi * 16 * 64 + ks * 32];
#pragma unroll
      for (int ni = 0; ni < 4; ++ni)
        bF[ni] = *(const bf16x8*)&lB[arow_b + ni * 16 * 64 + ks * 32];
#pragma unroll
      for (int mi = 0; mi < 4; ++mi)
#pragma unroll
        for (int ni = 0; ni < 4; ++ni)
          acc[mi][ni] = __builtin_amdgcn_mfma_f32_16x16x32_bf16(aF[mi], bF[ni],
                                                                acc[mi][ni], 0, 0, 0);
    }
    __syncthreads();
  }

#pragma unroll
  for (int mi = 0; mi < 4; ++mi) {
#pragma unroll
    for (int ni = 0; ni < 4; ++ni) {
      int m = bm0 + wr * 64 + mi * 16 + (ln >> 4) * 4;
      int n = bn0 + wc * 64 + ni * 16 + (ln & 15);
#pragma unroll
      for (int r = 0; r < 4; ++r) {
        float x = acc[mi][ni][r];
        float s = x / (1.f + __expf(-x));
        size_t o = (size_t)(m + r) * HID + n;
        out[o] = resid[o] + s;
      }
    }
  }
}

extern "C" void kernel_launch(void* const* d_in, const int* in_sizes, int n_in,
                              void* d_out, int out_size, void* d_ws, size_t ws_size,
                              hipStream_t stream) {
  const float* hid = (const float*)d_in[0];
  const float* Win = (const float*)d_in[1];
  const float* Wup = (const float*)d_in[2];
  float* out = (float*)d_out;
  char* ws = (char*)d_ws;

  unsigned short* Wb = (unsigned short*)ws;                    // 33,554,432 B
  unsigned short* hs = (unsigned short*)(ws + 33554432);       // 16,777,216 B
  float* part = (float*)(ws + 50331648);                       //  2,359,296 B
  float* params = (float*)(ws + 52690944);                     //      1,024 B

  k_cvt<<<16384, 256, 0, stream>>>(Win, Wb, HID * HID / 4);
  k_scores<<<NB * NH * NCHUNK, 256, 0, stream>>>(hid, part);
  k_head<<<NB * NH, 256, 0, stream>>>(part, params);
  k_copy<<<NB * 448 * (HID / 4) / 256, 256, 0, stream>>>(hid, hs);
  k_img<<<NB * NH * 4, 256, 0, stream>>>(hid, Wup, params, hs);
  k_gemm<<<512, 256, 0, stream>>>(hs, Wb, hid, out);
}

// Round 2
// 309.725 us; speedup vs baseline: 1.4246x; 1.4246x over previous
//
#include <hip/hip_runtime.h>
#include <hip/hip_bf16.h>
#include <math.h>

#define HID 4096
#define NH 32
#define HD 128
#define EDGE 24
#define KW 12
#define PEW 13
#define VT 576
#define OFF 5
#define NB 2
#define SLEN 1024
#define QT 32      // q rows per scores block
#define NQT 14     // q tiles per (b,h)  (448/32)
#define KT 32      // k rows per staged tile
#define NKT 32     // 1024/KT

typedef short bf16x8 __attribute__((ext_vector_type(8)));
typedef float f32x4 __attribute__((ext_vector_type(4)));
typedef unsigned int u32;

static __device__ __forceinline__ unsigned short f2bf(float f) {
  union { float f; u32 u; } v; v.f = f;
  u32 u = v.u;
  return (unsigned short)((u + 0x7fffu + ((u >> 16) & 1u)) >> 16);
}

static __device__ __forceinline__ float dot4(float4 a, float4 b) {
  return a.x * b.x + a.y * b.y + a.z * b.z + a.w * b.w;
}

static __device__ __forceinline__ void load_lds16(const void* g, void* l) {
  __builtin_amdgcn_global_load_lds((const __attribute__((address_space(1))) u32*)g,
                                   (__attribute__((address_space(3))) u32*)l, 16, 0, 0);
}

static __device__ __forceinline__ void extract8(uint4 a, uint4 b,
                                                bf16x8& hi, bf16x8& lo) {
  u32 w[8] = {a.x, a.y, a.z, a.w, b.x, b.y, b.z, b.w};
#pragma unroll
  for (int j = 0; j < 8; ++j) {
    hi[j] = (short)(w[j] >> 16);
    lo[j] = (short)(w[j] & 0xffffu);
  }
}

// ---------------- Kernel A: f32 -> bf16 convert (W_in) ----------------
__global__ __launch_bounds__(256) void k_cvt(const float* __restrict__ in,
                                             unsigned short* __restrict__ out, int n4) {
  int i = blockIdx.x * 256 + threadIdx.x;
  if (i < n4) {
    float4 v = ((const float4*)in)[i];
    ushort4 o;
    o.x = f2bf(v.x); o.y = f2bf(v.y); o.z = f2bf(v.z); o.w = f2bf(v.w);
    ((ushort4*)out)[i] = o;
  }
}

// ---------------- Kernel P: pack hidden -> (hi<<16)|lo u32, + non-image hs ----------------
__global__ __launch_bounds__(256) void k_pack(const float* __restrict__ hid,
                                              u32* __restrict__ P,
                                              unsigned short* __restrict__ hs) {
  int i = blockIdx.x * 256 + threadIdx.x;   // f32x4 index, total NB*SLEN*HID/4
  float4 x = ((const float4*)hid)[i];
  float e[4] = {x.x, x.y, x.z, x.w};
  u32 pk[4];
  unsigned short hb4[4];
#pragma unroll
  for (int j = 0; j < 4; ++j) {
    u32 u = __float_as_uint(e[j]);
    u32 hb = (u + 0x7fffu + ((u >> 16) & 1u)) >> 16;
    float hf = __uint_as_float(hb << 16);
    float r = e[j] - hf;
    u32 ur = __float_as_uint(r);
    u32 lb = (ur + 0x7fffu + ((ur >> 16) & 1u)) >> 16;
    pk[j] = (hb << 16) | lb;
    hb4[j] = (unsigned short)hb;
  }
  uint4 pv; pv.x = pk[0]; pv.y = pk[1]; pv.z = pk[2]; pv.w = pk[3];
  ((uint4*)P)[i] = pv;
  int s = (i >> 10) & (SLEN - 1);
  if (s < OFF || s >= OFF + VT) {
    ushort4 o; o.x = hb4[0]; o.y = hb4[1]; o.z = hb4[2]; o.w = hb4[3];
    ((ushort4*)hs)[i] = o;
  }
}

// ---------------- Kernel B: MFMA hi/lo scores + softmax + partial colsums ----------------
// grid = NB*NH*NQT; block = 256 (4 waves). Wave (wq,wk): q-frag wq (16 rows),
// k-frag wk (16 of the 32-col staged tile). S stored transposed+swizzled in LDS.
__global__ __launch_bounds__(256) void k_scores(const u32* __restrict__ P,
                                                float* __restrict__ part) {
  __shared__ float S[SLEN * QT];      // 131072 B, S_T: [col][32] with 16B-blk XOR swizzle
  __shared__ u32 Kt[KT * HD];         // 16384 B
  __shared__ float Mrow[QT];
  __shared__ float ZIrow[QT];

  int bid = blockIdx.x;
  int qt = bid % NQT;
  int bh = bid / NQT;
  int b = bh >> 5, h = bh & 31;
  int t = threadIdx.x;
  int l = t & 63, wv = t >> 6;
  int wq = wv >> 1, wk = wv & 1;

  const u32* Pb = P + (size_t)b * SLEN * HID + h * HD;

  // ---- Q fragments for this wave's 16 q rows (registers, reused all tiles) ----
  bf16x8 qhi[4], qlo[4];
  {
    int ql = qt * QT + wq * 16 + (l & 15);
    int qg = (ql < OFF) ? ql : ql + VT;
    const u32* qp = Pb + (size_t)qg * HID;
#pragma unroll
    for (int ds = 0; ds < 4; ++ds) {
      int dbase = ds * 32 + (l >> 4) * 8;
      uint4 a = *(const uint4*)(qp + dbase);
      uint4 bq = *(const uint4*)(qp + dbase + 4);
      extract8(a, bq, qhi[ds], qlo[ds]);
    }
  }

  // staging: thread t owns u32s [t*16, t*16+16) of the 32x128 tile
  int srow = t >> 3;
  int scol = (t & 7) * 16;
  const float scale = 0.088388347648318447f;  // 1/sqrt(128)

  uint4 rg0, rg1, rg2, rg3;
  {
    const u32* src = Pb + (size_t)srow * HID + scol;
    rg0 = *(const uint4*)(src + 0);
    rg1 = *(const uint4*)(src + 4);
    rg2 = *(const uint4*)(src + 8);
    rg3 = *(const uint4*)(src + 12);
  }
  {
    uint4* dst = (uint4*)&Kt[t * 16];
    dst[0] = rg0; dst[1] = rg1; dst[2] = rg2; dst[3] = rg3;
  }
  __syncthreads();

  for (int kt = 0; kt < NKT; ++kt) {
    // issue next tile's global loads early (latency hides under MFMA)
    if (kt + 1 < NKT) {
      const u32* src = Pb + (size_t)((kt + 1) * KT + srow) * HID + scol;
      rg0 = *(const uint4*)(src + 0);
      rg1 = *(const uint4*)(src + 4);
      rg2 = *(const uint4*)(src + 8);
      rg3 = *(const uint4*)(src + 12);
    }

    f32x4 accA = {0.f, 0.f, 0.f, 0.f};
    f32x4 accB = {0.f, 0.f, 0.f, 0.f};
#pragma unroll
    for (int ds = 0; ds < 4; ++ds) {
      int bidx = (wk * 16 + (l & 15)) * HD + ds * 32 + (l >> 4) * 8;
      uint4 w0 = *(const uint4*)&Kt[bidx];
      uint4 w1 = *(const uint4*)&Kt[bidx + 4];
      bf16x8 khi, klo;
      extract8(w0, w1, khi, klo);
      if (ds & 1) {
        accB = __builtin_amdgcn_mfma_f32_16x16x32_bf16(qhi[ds], khi, accB, 0, 0, 0);
        accB = __builtin_amdgcn_mfma_f32_16x16x32_bf16(qhi[ds], klo, accB, 0, 0, 0);
        accB = __builtin_amdgcn_mfma_f32_16x16x32_bf16(qlo[ds], khi, accB, 0, 0, 0);
      } else {
        accA = __builtin_amdgcn_mfma_f32_16x16x32_bf16(qhi[ds], khi, accA, 0, 0, 0);
        accA = __builtin_amdgcn_mfma_f32_16x16x32_bf16(qhi[ds], klo, accA, 0, 0, 0);
        accA = __builtin_amdgcn_mfma_f32_16x16x32_bf16(qlo[ds], khi, accA, 0, 0, 0);
      }
    }

    // write S tile (transposed, swizzled): col = k index, rows = q
    {
      int col = kt * KT + wk * 16 + (l & 15);
      int g = wq * 4 + (l >> 4);
      f32x4 sv;
#pragma unroll
      for (int j = 0; j < 4; ++j) sv[j] = (accA[j] + accB[j]) * scale;
      *(f32x4*)&S[col * QT + ((g * 4) ^ ((col & 7) << 2))] = sv;
    }

    __syncthreads();   // all waves done reading Kt (and S writes flushed on last iter)
    if (kt + 1 < NKT) {
      uint4* dst = (uint4*)&Kt[t * 16];
      dst[0] = rg0; dst[1] = rg1; dst[2] = rg2; dst[3] = rg3;
      __syncthreads(); // Kt ready
    }
  }
  __syncthreads();

  // ---- row stats: thread t -> row r = t>>3, sub-lane j = t&7 scans 128 cols ----
  {
    int r = t >> 3, j = t & 7;
    float m = -3.4e38f;
    for (int i = 0; i < 128; ++i) {
      int c = j + 8 * i;
      m = fmaxf(m, S[c * QT + (r ^ ((c & 7) << 2))]);
    }
#pragma unroll
    for (int o = 1; o < 8; o <<= 1) m = fmaxf(m, __shfl_xor(m, o));
    float z = 0.f;
    for (int i = 0; i < 128; ++i) {
      int c = j + 8 * i;
      z += __expf(S[c * QT + (r ^ ((c & 7) << 2))] - m);
    }
#pragma unroll
    for (int o = 1; o < 8; o <<= 1) z += __shfl_xor(z, o);
    if (j == 0) { Mrow[r] = m; ZIrow[r] = 1.f / z; }
  }
  __syncthreads();

  // ---- colsums for the 576 image columns ----
  for (int c5 = t; c5 < VT; c5 += 256) {
    int col = OFF + c5;
    float cs = 0.f;
    int cb = col * QT;
    int sw = (col & 7) << 2;
#pragma unroll
    for (int g2 = 0; g2 < 8; ++g2) {
      f32x4 v = *(const f32x4*)&S[cb + ((g2 * 4) ^ sw)];
#pragma unroll
      for (int j2 = 0; j2 < 4; ++j2) {
        int r = g2 * 4 + j2;
        cs += __expf(v[j2] - Mrow[r]) * ZIrow[r];
      }
    }
    part[((size_t)bh * NQT + qt) * VT + c5] = cs;
  }
}

// ---------------- Kernel C: per-head softmax / pool / argmax / w ----------------
__global__ __launch_bounds__(256) void k_head(const float* __restrict__ part,
                                              float* __restrict__ params) {
  int bh = blockIdx.x;
  int t = threadIdx.x;
  __shared__ float ia[VT];
  __shared__ float sfe[VT];
  __shared__ float rbuf[256];
  __shared__ int ribuf[256];

  for (int i = t; i < VT; i += 256) {
    float s = 0.f;
    const float* p = part + (size_t)bh * NQT * VT + i;
    for (int c = 0; c < NQT; ++c) s += p[(size_t)c * VT];
    ia[i] = s;
  }
  __syncthreads();

  float lm = -1e30f;
  for (int i = t; i < VT; i += 256) lm = fmaxf(lm, ia[i]);
  rbuf[t] = lm;
  __syncthreads();
  for (int s = 128; s > 0; s >>= 1) {
    if (t < s) rbuf[t] = fmaxf(rbuf[t], rbuf[t + s]);
    __syncthreads();
  }
  float M = rbuf[0];
  __syncthreads();

  float lz = 0.f;
  for (int i = t; i < VT; i += 256) {
    float e = __expf(ia[i] - M);
    sfe[i] = e;
    lz += e;
  }
  rbuf[t] = lz;
  __syncthreads();
  for (int s = 128; s > 0; s >>= 1) {
    if (t < s) rbuf[t] += rbuf[t + s];
    __syncthreads();
  }
  float invZ = 1.f / rbuf[0];
  __syncthreads();

  float pv = -1e30f;
  int pidx = 0x7fffffff;
  if (t < PEW * PEW) {
    int r = t / PEW, c = t % PEW;
    float s = 0.f;
    for (int i = 0; i < KW; ++i)
      for (int j = 0; j < KW; ++j) s += ia[(r + i) * EDGE + (c + j)];
    pv = s;
    pidx = t;
  }
  rbuf[t] = pv;
  ribuf[t] = pidx;
  __syncthreads();
  for (int s = 128; s > 0; s >>= 1) {
    if (t < s) {
      float ov = rbuf[t + s];
      int oi = ribuf[t + s];
      if (ov > rbuf[t] || (ov == rbuf[t] && oi < ribuf[t])) {
        rbuf[t] = ov;
        ribuf[t] = oi;
      }
    }
    __syncthreads();
  }
  int idx = ribuf[0];
  int r0 = idx / PEW, c0 = idx % PEW;
  __syncthreads();

  float lw = 0.f;
  if (t < KW * KW) {
    int i = t / KW, j = t % KW;
    lw = sfe[(r0 + i) * EDGE + (c0 + j)];
  }
  rbuf[t] = lw;
  __syncthreads();
  for (int s = 128; s > 0; s >>= 1) {
    if (t < s) rbuf[t] += rbuf[t + s];
    __syncthreads();
  }
  if (t == 0) {
    params[bh * 4 + 0] = rbuf[0] * invZ;
    ((int*)params)[bh * 4 + 1] = r0;
    ((int*)params)[bh * 4 + 2] = c0;
  }
}

// ---------------- Kernel D2: per-head window up-projection -> bf16 hs ----------------
__global__ __launch_bounds__(256) void k_img(const float* __restrict__ hid,
                                             const float* __restrict__ Wup,
                                             const float* __restrict__ params,
                                             unsigned short* __restrict__ hs) {
  int bid = blockIdx.x;
  int g = bid & 3;
  int bh = bid >> 2;
  int b = bh / NH, h = bh % NH;
  float w = params[bh * 4];
  int r0 = ((const int*)params)[bh * 4 + 1];
  int c0 = ((const int*)params)[bh * 4 + 2];
  int t = threadIdx.x;

  __shared__ float win[36][HD];
  for (int idx = t; idx < 36 * (HD / 4); idx += 256) {
    int cell = idx >> 5;
    int c4 = idx & 31;
    int cc = g * 36 + cell;
    int i = cc / 12, j = cc % 12;
    int s = OFF + (r0 + i) * EDGE + (c0 + j);
    *(float4*)&win[cell][c4 * 4] =
        *(const float4*)(hid + ((size_t)(b * SLEN + s)) * HID + h * HD + c4 * 4);
  }
  __syncthreads();

  float acc0[36], acc1[36];
#pragma unroll
  for (int cell = 0; cell < 36; ++cell) { acc0[cell] = 0.f; acc1[cell] = 0.f; }

  int e0 = t, e1 = t + 256;
  const float* w0 = Wup + (size_t)e0 * HD;
  const float* w1 = Wup + (size_t)e1 * HD;
  for (int c = 0; c < 32; ++c) {
    float4 u0 = *(const float4*)(w0 + c * 4);
    float4 u1 = *(const float4*)(w1 + c * 4);
#pragma unroll
    for (int cell = 0; cell < 36; ++cell) {
      float4 qv = *(const float4*)&win[cell][c * 4];
      acc0[cell] += dot4(qv, u0);
      acc1[cell] += dot4(qv, u1);
    }
  }

  int si0 = e0 >> 8, sj0 = (e0 >> 7) & 1, d0 = e0 & 127;
  int si1 = e1 >> 8, sj1 = (e1 >> 7) & 1, d1 = e1 & 127;
#pragma unroll
  for (int cell = 0; cell < 36; ++cell) {
    int cc = g * 36 + cell;
    int i = cc / 12, j = cc % 12;
    {
      int srow = OFF + (2 * i + si0) * EDGE + (2 * j + sj0);
      hs[((size_t)(b * SLEN + srow)) * HID + h * HD + d0] = f2bf(acc0[cell] * w);
    }
    {
      int srow = OFF + (2 * i + si1) * EDGE + (2 * j + sj1);
      hs[((size_t)(b * SLEN + srow)) * HID + h * HD + d1] = f2bf(acc1[cell] * w);
    }
  }
}

// ---------------- Kernel E: bf16 MFMA GEMM, silu + residual epilogue ----------------
__global__ __launch_bounds__(256) void k_gemm(const unsigned short* __restrict__ A,
                                              const unsigned short* __restrict__ Bm,
                                              const float* __restrict__ resid,
                                              float* __restrict__ out) {
  int bid = blockIdx.x;
  int bm0 = (bid & 15) << 7;
  int bn0 = (bid >> 4) << 7;
  int t = threadIdx.x;
  int ln = t & 63, wv = t >> 6;
  int wr = wv >> 1, wc = wv & 1;

  __shared__ unsigned short lA[128 * 64];
  __shared__ unsigned short lB[128 * 64];

  f32x4 acc[4][4];
#pragma unroll
  for (int mi = 0; mi < 4; ++mi)
#pragma unroll
    for (int ni = 0; ni < 4; ++ni) acc[mi][ni] = (f32x4){0.f, 0.f, 0.f, 0.f};

  const unsigned short* aptr = A + (size_t)(bm0 + (t >> 3)) * HID + (t & 7) * 8;
  const unsigned short* bptr = Bm + (size_t)(bn0 + (t >> 3)) * HID + (t & 7) * 8;
  unsigned short* la = &lA[t * 8];
  unsigned short* lb = &lB[t * 8];

  int arow_a = (wr * 64 + (ln & 15)) * 64 + (ln >> 4) * 8;
  int arow_b = (wc * 64 + (ln & 15)) * 64 + (ln >> 4) * 8;

  for (int k0 = 0; k0 < HID; k0 += 64) {
#pragma unroll
    for (int i = 0; i < 4; ++i)
      load_lds16(aptr + (size_t)i * 32 * HID + k0, la + i * 2048);
#pragma unroll
    for (int i = 0; i < 4; ++i)
      load_lds16(bptr + (size_t)i * 32 * HID + k0, lb + i * 2048);
    __syncthreads();
#pragma unroll
    for (int ks = 0; ks < 2; ++ks) {
      bf16x8 aF[4], bF[4];
#pragma unroll
      for (int mi = 0; mi < 4; ++mi)
        aF[mi] = *(const bf16x8*)&lA[arow_a + mi * 16 * 64 + ks * 32];
#pragma unroll
      for (int ni = 0; ni < 4; ++ni)
        bF[ni] = *(const bf16x8*)&lB[arow_b + ni * 16 * 64 + ks * 32];
#pragma unroll
      for (int mi = 0; mi < 4; ++mi)
#pragma unroll
        for (int ni = 0; ni < 4; ++ni)
          acc[mi][ni] = __builtin_amdgcn_mfma_f32_16x16x32_bf16(aF[mi], bF[ni],
                                                                acc[mi][ni], 0, 0, 0);
    }
    __syncthreads();
  }

#pragma unroll
  for (int mi = 0; mi < 4; ++mi) {
#pragma unroll
    for (int ni = 0; ni < 4; ++ni) {
      int m = bm0 + wr * 64 + mi * 16 + (ln >> 4) * 4;
      int n = bn0 + wc * 64 + ni * 16 + (ln & 15);
#pragma unroll
      for (int r = 0; r < 4; ++r) {
        float x = acc[mi][ni][r];
        float s = x / (1.f + __expf(-x));
        size_t o = (size_t)(m + r) * HID + n;
        out[o] = resid[o] + s;
      }
    }
  }
}

extern "C" void kernel_launch(void* const* d_in, const int* in_sizes, int n_in,
                              void* d_out, int out_size, void* d_ws, size_t ws_size,
                              hipStream_t stream) {
  const float* hid = (const float*)d_in[0];
  const float* Win = (const float*)d_in[1];
  const float* Wup = (const float*)d_in[2];
  float* out = (float*)d_out;
  char* ws = (char*)d_ws;

  unsigned short* Wb = (unsigned short*)ws;                 // 33,554,432 B
  unsigned short* hs = (unsigned short*)(ws + 33554432);    // 16,777,216 B
  float* part = (float*)(ws + 50331648);                    //  2,064,384 B
  float* params = (float*)(ws + 52396032);                  //      1,024 B
  u32* P = (u32*)d_out;  // packed hi/lo hidden lives in d_out until k_gemm overwrites it

  k_cvt<<<16384, 256, 0, stream>>>(Win, Wb, HID * HID / 4);
  k_pack<<<NB * SLEN * HID / 4 / 256, 256, 0, stream>>>(hid, P, hs);
  k_scores<<<NB * NH * NQT, 256, 0, stream>>>(P, part);
  k_head<<<NB * NH, 256, 0, stream>>>(part, params);
  k_img<<<NB * NH * 4, 256, 0, stream>>>(hid, Wup, params, hs);
  k_gemm<<<512, 256, 0, stream>>>(hs, Wb, hid, out);
}

// Round 3
// 276.600 us; speedup vs baseline: 1.5952x; 1.1198x over previous
//
#include <hip/hip_runtime.h>
#include <hip/hip_bf16.h>
#include <math.h>

#define HID 4096
#define NH 32
#define HD 128
#define EDGE 24
#define KW 12
#define PEW 13
#define VT 576
#define OFF 5
#define NB 2
#define SLEN 1024
#define QT 32      // q rows per scores block
#define NQT 14     // q tiles per (b,h)  (448/32)
#define KT 32      // k rows per staged tile
#define NKT 32     // 1024/KT

typedef short bf16x8 __attribute__((ext_vector_type(8)));
typedef float f32x4 __attribute__((ext_vector_type(4)));
typedef unsigned int u32;

static __device__ __forceinline__ unsigned short f2bf(float f) {
  union { float f; u32 u; } v; v.f = f;
  u32 u = v.u;
  return (unsigned short)((u + 0x7fffu + ((u >> 16) & 1u)) >> 16);
}

static __device__ __forceinline__ float dot4(float4 a, float4 b) {
  return a.x * b.x + a.y * b.y + a.z * b.z + a.w * b.w;
}

static __device__ __forceinline__ void load_lds16(const void* g, void* l) {
  __builtin_amdgcn_global_load_lds((const __attribute__((address_space(1))) u32*)g,
                                   (__attribute__((address_space(3))) u32*)l, 16, 0, 0);
}

// ---------------- Kernel A: f32 -> bf16 convert (W_in) ----------------
__global__ __launch_bounds__(256) void k_cvt(const float* __restrict__ in,
                                             unsigned short* __restrict__ out, int n4) {
  int i = blockIdx.x * 256 + threadIdx.x;
  if (i < n4) {
    float4 v = ((const float4*)in)[i];
    ushort4 o;
    o.x = f2bf(v.x); o.y = f2bf(v.y); o.z = f2bf(v.z); o.w = f2bf(v.w);
    ((ushort4*)out)[i] = o;
  }
}

// ---------------- Kernel P: split hidden -> bf16 hi plane + lo plane ----------------
// Phi = bf16(x); Plo = bf16(x - f32(Phi)). Phi later doubles as the GEMM A matrix.
__global__ __launch_bounds__(256) void k_pack(const float* __restrict__ hid,
                                              unsigned short* __restrict__ Phi,
                                              unsigned short* __restrict__ Plo) {
  int i = blockIdx.x * 256 + threadIdx.x;   // f32x4 index, total NB*SLEN*HID/4
  float4 x = ((const float4*)hid)[i];
  float e[4] = {x.x, x.y, x.z, x.w};
  ushort4 hv, lv;
  unsigned short* hp = (unsigned short*)&hv;
  unsigned short* lp = (unsigned short*)&lv;
#pragma unroll
  for (int j = 0; j < 4; ++j) {
    u32 u = __float_as_uint(e[j]);
    u32 hb = (u + 0x7fffu + ((u >> 16) & 1u)) >> 16;
    float r = e[j] - __uint_as_float(hb << 16);
    u32 ur = __float_as_uint(r);
    u32 lb = (ur + 0x7fffu + ((ur >> 16) & 1u)) >> 16;
    hp[j] = (unsigned short)hb;
    lp[j] = (unsigned short)lb;
  }
  ((ushort4*)Phi)[i] = hv;
  ((ushort4*)Plo)[i] = lv;
}

// ---------------- Kernel B: two-pass MFMA scores, no S storage ----------------
// grid = 896 (XCD-grouped). Block: one (b,h), 32 q rows. 4 waves: wq=wv&1 (row
// half), wk=wv>>1 (k half of each 32-col tile). Pass 1: z per row (registers).
// Pass 2: recompute scores, emit exp(s)/z colsums via shfl reduce into LDS cs.
__global__ __launch_bounds__(256) void k_scores(const unsigned short* __restrict__ Phi,
                                                const unsigned short* __restrict__ Plo,
                                                float* __restrict__ part) {
  __shared__ unsigned short Kh[2][KT * HD];   // 8 KB per buffer
  __shared__ unsigned short Kl[2][KT * HD];
  __shared__ float cs[4][SLEN];               // 16 KB
  __shared__ float zbuf[2][QT];

  int bid = blockIdx.x;
  int xr = bid & 7, sl = bid >> 3;            // group same-bh blocks on one XCD
  int bh = xr * 8 + sl / NQT;
  int qt = sl % NQT;
  int b = bh >> 5, h = bh & 31;
  int t = threadIdx.x, l = t & 63, wv = t >> 6;
  int wq = wv & 1, wk = wv >> 1;

  const unsigned short* PhB = Phi + (size_t)b * SLEN * HID + h * HD;
  const unsigned short* PlB = Plo + (size_t)b * SLEN * HID + h * HD;

  // ---- Q fragments (registers, reused across all tiles) ----
  bf16x8 qhi[4], qlo[4];
  {
    int ql = qt * QT + wq * 16 + (l & 15);
    int qg = (ql < OFF) ? ql : ql + VT;
    const unsigned short* ph = PhB + (size_t)qg * HID + (l >> 4) * 8;
    const unsigned short* pl = PlB + (size_t)qg * HID + (l >> 4) * 8;
#pragma unroll
    for (int ds = 0; ds < 4; ++ds) {
      qhi[ds] = *(const bf16x8*)(ph + ds * 32);
      qlo[ds] = *(const bf16x8*)(pl + ds * 32);
    }
  }

  // staging: linear LDS dest (lane*16B), inverse-swizzled global source.
  // granule g = (wv*2+i)*64 + l; row = g>>4; stored col-granule c' = g&15
  // holds global col-granule c = c' ^ (row&7).
  int sg0 = (wv * 2 + 0) * 64 + l;
  int sg1 = (wv * 2 + 1) * 64 + l;
  int srow0 = sg0 >> 4, srow1 = sg1 >> 4;
  size_t soff0 = (size_t)srow0 * HID + ((sg0 & 15) ^ (srow0 & 7)) * 8;
  size_t soff1 = (size_t)srow1 * HID + ((sg1 & 15) ^ (srow1 & 7)) * 8;

#define STAGE(kt_, bb_)                                                        \
  do {                                                                         \
    size_t kb_ = (size_t)(kt_)*KT * HID;                                       \
    load_lds16(PhB + kb_ + soff0, &Kh[bb_][sg0 * 8]);                          \
    load_lds16(PlB + kb_ + soff0, &Kl[bb_][sg0 * 8]);                          \
    load_lds16(PhB + kb_ + soff1, &Kh[bb_][sg1 * 8]);                          \
    load_lds16(PlB + kb_ + soff1, &Kl[bb_][sg1 * 8]);                          \
  } while (0)

  float zacc[4] = {0.f, 0.f, 0.f, 0.f};
  float zinv[4];
  const float scale = 0.088388347648318447f;  // 1/sqrt(128)

  // read-fragment offsets (XOR-swizzled): row = wk*16 + (l&15)
  int frow = wk * 16 + (l & 15);
  int foff[4];
#pragma unroll
  for (int ds = 0; ds < 4; ++ds)
    foff[ds] = frow * HD + (((ds * 4) + (l >> 4)) ^ (frow & 7)) * 8;

  STAGE(0, 0);
  __syncthreads();

  for (int tt = 0; tt < 2 * NKT; ++tt) {
    int kt = tt & (NKT - 1);
    int bb = tt & 1;
    if (tt + 1 < 2 * NKT) STAGE((tt + 1) & (NKT - 1), bb ^ 1);

    if (tt == NKT) {  // finalize zinv (zbuf written at tt==NKT-1, barrier passed)
#pragma unroll
      for (int j = 0; j < 4; ++j) {
        int row = wq * 16 + (l >> 4) * 4 + j;
        zinv[j] = 1.f / (zbuf[0][row] + zbuf[1][row]);
      }
    }

    // 3 independent MFMA chains: hi*hi, hi*lo, lo*hi
    f32x4 aP = {0.f, 0.f, 0.f, 0.f};
    f32x4 aQ = {0.f, 0.f, 0.f, 0.f};
    f32x4 aR = {0.f, 0.f, 0.f, 0.f};
#pragma unroll
    for (int ds = 0; ds < 4; ++ds) {
      bf16x8 kh = *(const bf16x8*)&Kh[bb][foff[ds]];
      bf16x8 kl = *(const bf16x8*)&Kl[bb][foff[ds]];
      aP = __builtin_amdgcn_mfma_f32_16x16x32_bf16(qhi[ds], kh, aP, 0, 0, 0);
      aQ = __builtin_amdgcn_mfma_f32_16x16x32_bf16(qhi[ds], kl, aQ, 0, 0, 0);
      aR = __builtin_amdgcn_mfma_f32_16x16x32_bf16(qlo[ds], kh, aR, 0, 0, 0);
    }

    if (tt < NKT) {
#pragma unroll
      for (int j = 0; j < 4; ++j)
        zacc[j] += __expf((aP[j] + aQ[j] + aR[j]) * scale);
    } else {
      float v = 0.f;
#pragma unroll
      for (int j = 0; j < 4; ++j)
        v += __expf((aP[j] + aQ[j] + aR[j]) * scale) * zinv[j];
      v += __shfl_xor(v, 16);
      v += __shfl_xor(v, 32);
      if (l < 16) cs[wv][kt * KT + wk * 16 + l] = v;
    }

    if (tt == NKT - 1) {
#pragma unroll
      for (int j = 0; j < 4; ++j) {
        float z = zacc[j];
        z += __shfl_xor(z, 1);
        z += __shfl_xor(z, 2);
        z += __shfl_xor(z, 4);
        z += __shfl_xor(z, 8);
        if ((l & 15) == 0) zbuf[wk][wq * 16 + (l >> 4) * 4 + j] = z;
      }
    }
    __syncthreads();
  }

  // combine the two wq halves; col's k-half kb selects which wave pair wrote it
  for (int c5 = t; c5 < VT; c5 += 256) {
    int col = OFF + c5;
    int kb = (col >> 4) & 1;
    part[((size_t)bh * NQT + qt) * VT + c5] = cs[kb * 2][col] + cs[kb * 2 + 1][col];
  }
#undef STAGE
}

// ---------------- Kernel C: per-head softmax / pool / argmax / w ----------------
__global__ __launch_bounds__(256) void k_head(const float* __restrict__ part,
                                              float* __restrict__ params) {
  int bh = blockIdx.x;
  int t = threadIdx.x;
  __shared__ float ia[VT];
  __shared__ float sfe[VT];
  __shared__ float rbuf[256];
  __shared__ int ribuf[256];

  for (int i = t; i < VT; i += 256) {
    float s = 0.f;
    const float* p = part + (size_t)bh * NQT * VT + i;
    for (int c = 0; c < NQT; ++c) s += p[(size_t)c * VT];
    ia[i] = s;
  }
  __syncthreads();

  float lm = -1e30f;
  for (int i = t; i < VT; i += 256) lm = fmaxf(lm, ia[i]);
  rbuf[t] = lm;
  __syncthreads();
  for (int s = 128; s > 0; s >>= 1) {
    if (t < s) rbuf[t] = fmaxf(rbuf[t], rbuf[t + s]);
    __syncthreads();
  }
  float M = rbuf[0];
  __syncthreads();

  float lz = 0.f;
  for (int i = t; i < VT; i += 256) {
    float e = __expf(ia[i] - M);
    sfe[i] = e;
    lz += e;
  }
  rbuf[t] = lz;
  __syncthreads();
  for (int s = 128; s > 0; s >>= 1) {
    if (t < s) rbuf[t] += rbuf[t + s];
    __syncthreads();
  }
  float invZ = 1.f / rbuf[0];
  __syncthreads();

  float pv = -1e30f;
  int pidx = 0x7fffffff;
  if (t < PEW * PEW) {
    int r = t / PEW, c = t % PEW;
    float s = 0.f;
    for (int i = 0; i < KW; ++i)
      for (int j = 0; j < KW; ++j) s += ia[(r + i) * EDGE + (c + j)];
    pv = s;
    pidx = t;
  }
  rbuf[t] = pv;
  ribuf[t] = pidx;
  __syncthreads();
  for (int s = 128; s > 0; s >>= 1) {
    if (t < s) {
      float ov = rbuf[t + s];
      int oi = ribuf[t + s];
      if (ov > rbuf[t] || (ov == rbuf[t] && oi < ribuf[t])) {
        rbuf[t] = ov;
        ribuf[t] = oi;
      }
    }
    __syncthreads();
  }
  int idx = ribuf[0];
  int r0 = idx / PEW, c0 = idx % PEW;
  __syncthreads();

  float lw = 0.f;
  if (t < KW * KW) {
    int i = t / KW, j = t % KW;
    lw = sfe[(r0 + i) * EDGE + (c0 + j)];
  }
  rbuf[t] = lw;
  __syncthreads();
  for (int s = 128; s > 0; s >>= 1) {
    if (t < s) rbuf[t] += rbuf[t + s];
    __syncthreads();
  }
  if (t == 0) {
    params[bh * 4 + 0] = rbuf[0] * invZ;
    ((int*)params)[bh * 4 + 1] = r0;
    ((int*)params)[bh * 4 + 2] = c0;
  }
}

// ---------------- Kernel D2: per-head window up-projection -> bf16 into Phi ----------------
__global__ __launch_bounds__(256) void k_img(const float* __restrict__ hid,
                                             const float* __restrict__ Wup,
                                             const float* __restrict__ params,
                                             unsigned short* __restrict__ hs) {
  int bid = blockIdx.x;
  int g = bid & 3;
  int bh = bid >> 2;
  int b = bh / NH, h = bh % NH;
  float w = params[bh * 4];
  int r0 = ((const int*)params)[bh * 4 + 1];
  int c0 = ((const int*)params)[bh * 4 + 2];
  int t = threadIdx.x;

  __shared__ float win[36][HD];
  for (int idx = t; idx < 36 * (HD / 4); idx += 256) {
    int cell = idx >> 5;
    int c4 = idx & 31;
    int cc = g * 36 + cell;
    int i = cc / 12, j = cc % 12;
    int s = OFF + (r0 + i) * EDGE + (c0 + j);
    *(float4*)&win[cell][c4 * 4] =
        *(const float4*)(hid + ((size_t)(b * SLEN + s)) * HID + h * HD + c4 * 4);
  }
  __syncthreads();

  float acc0[36], acc1[36];
#pragma unroll
  for (int cell = 0; cell < 36; ++cell) { acc0[cell] = 0.f; acc1[cell] = 0.f; }

  int e0 = t, e1 = t + 256;
  const float* w0 = Wup + (size_t)e0 * HD;
  const float* w1 = Wup + (size_t)e1 * HD;
  for (int c = 0; c < 32; ++c) {
    float4 u0 = *(const float4*)(w0 + c * 4);
    float4 u1 = *(const float4*)(w1 + c * 4);
#pragma unroll
    for (int cell = 0; cell < 36; ++cell) {
      float4 qv = *(const float4*)&win[cell][c * 4];
      acc0[cell] += dot4(qv, u0);
      acc1[cell] += dot4(qv, u1);
    }
  }

  int si0 = e0 >> 8, sj0 = (e0 >> 7) & 1, d0 = e0 & 127;
  int si1 = e1 >> 8, sj1 = (e1 >> 7) & 1, d1 = e1 & 127;
#pragma unroll
  for (int cell = 0; cell < 36; ++cell) {
    int cc = g * 36 + cell;
    int i = cc / 12, j = cc % 12;
    {
      int srow = OFF + (2 * i + si0) * EDGE + (2 * j + sj0);
      hs[((size_t)(b * SLEN + srow)) * HID + h * HD + d0] = f2bf(acc0[cell] * w);
    }
    {
      int srow = OFF + (2 * i + si1) * EDGE + (2 * j + sj1);
      hs[((size_t)(b * SLEN + srow)) * HID + h * HD + d1] = f2bf(acc1[cell] * w);
    }
  }
}

// ---------------- Kernel E: bf16 MFMA GEMM, silu + residual epilogue ----------------
__global__ __launch_bounds__(256) void k_gemm(const unsigned short* __restrict__ A,
                                              const unsigned short* __restrict__ Bm,
                                              const float* __restrict__ resid,
                                              float* __restrict__ out) {
  int bid = blockIdx.x;
  int bm0 = (bid & 15) << 7;
  int bn0 = (bid >> 4) << 7;
  int t = threadIdx.x;
  int ln = t & 63, wv = t >> 6;
  int wr = wv >> 1, wc = wv & 1;

  __shared__ unsigned short lA[128 * 64];
  __shared__ unsigned short lB[128 * 64];

  f32x4 acc[4][4];
#pragma unroll
  for (int mi = 0; mi < 4; ++mi)
#pragma unroll
    for (int ni = 0; ni < 4; ++ni) acc[mi][ni] = (f32x4){0.f, 0.f, 0.f, 0.f};

  const unsigned short* aptr = A + (size_t)(bm0 + (t >> 3)) * HID + (t & 7) * 8;
  const unsigned short* bptr = Bm + (size_t)(bn0 + (t >> 3)) * HID + (t & 7) * 8;
  unsigned short* la = &lA[t * 8];
  unsigned short* lb = &lB[t * 8];

  int arow_a = (wr * 64 + (ln & 15)) * 64 + (ln >> 4) * 8;
  int arow_b = (wc * 64 + (ln & 15)) * 64 + (ln >> 4) * 8;

  for (int k0 = 0; k0 < HID; k0 += 64) {
#pragma unroll
    for (int i = 0; i < 4; ++i)
      load_lds16(aptr + (size_t)i * 32 * HID + k0, la + i * 2048);
#pragma unroll
    for (int i = 0; i < 4; ++i)
      load_lds16(bptr + (size_t)i * 32 * HID + k0, lb + i * 2048);
    __syncthreads();
#pragma unroll
    for (int ks = 0; ks < 2; ++ks) {
      bf16x8 aF[4], bF[4];
#pragma unroll
      for (int mi = 0; mi < 4; ++mi)
        aF[mi] = *(const bf16x8*)&lA[arow_a + mi * 16 * 64 + ks * 32];
#pragma unroll
      for (int ni = 0; ni < 4; ++ni)
        bF[ni] = *(const bf16x8*)&lB[arow_b + ni * 16 * 64 + ks * 32];
#pragma unroll
      for (int mi = 0; mi < 4; ++mi)
#pragma unroll
        for (int ni = 0; ni < 4; ++ni)
          acc[mi][ni] = __builtin_amdgcn_mfma_f32_16x16x32_bf16(aF[mi], bF[ni],
                                                                acc[mi][ni], 0, 0, 0);
    }
    __syncthreads();
  }

#pragma unroll
  for (int mi = 0; mi < 4; ++mi) {
#pragma unroll
    for (int ni = 0; ni < 4; ++ni) {
      int m = bm0 + wr * 64 + mi * 16 + (ln >> 4) * 4;
      int n = bn0 + wc * 64 + ni * 16 + (ln & 15);
#pragma unroll
      for (int r = 0; r < 4; ++r) {
        float x = acc[mi][ni][r];
        float s = x / (1.f + __expf(-x));
        size_t o = (size_t)(m + r) * HID + n;
        out[o] = resid[o] + s;
      }
    }
  }
}

extern "C" void kernel_launch(void* const* d_in, const int* in_sizes, int n_in,
                              void* d_out, int out_size, void* d_ws, size_t ws_size,
                              hipStream_t stream) {
  const float* hid = (const float*)d_in[0];
  const float* Win = (const float*)d_in[1];
  const float* Wup = (const float*)d_in[2];
  float* out = (float*)d_out;
  char* ws = (char*)d_ws;

  unsigned short* Wb  = (unsigned short*)ws;                 // 33,554,432 B
  unsigned short* Phi = (unsigned short*)(ws + 33554432);    // 16,777,216 B
  float* part = (float*)(ws + 50331648);                     //  2,064,384 B
  float* params = (float*)(ws + 52396032);                   //      1,024 B
  unsigned short* Plo = (unsigned short*)d_out;  // lo plane lives in d_out until k_gemm

  k_cvt<<<16384, 256, 0, stream>>>(Win, Wb, HID * HID / 4);
  k_pack<<<NB * SLEN * HID / 4 / 256, 256, 0, stream>>>(hid, Phi, Plo);
  k_scores<<<NB * NH * NQT, 256, 0, stream>>>(Phi, Plo, part);
  k_head<<<NB * NH, 256, 0, stream>>>(part, params);
  k_img<<<NB * NH * 4, 256, 0, stream>>>(hid, Wup, params, Phi);
  k_gemm<<<512, 256, 0, stream>>>(Phi, Wb, hid, out);
}

// Round 4
// 246.667 us; speedup vs baseline: 1.7888x; 1.1214x over previous
//
#include <hip/hip_runtime.h>
#include <hip/hip_bf16.h>
#include <math.h>

#define HID 4096
#define NH 32
#define HD 128
#define EDGE 24
#define KW 12
#define PEW 13
#define VT 576
#define OFF 5
#define NB 2
#define SLEN 1024
#define QT 32      // q rows per scores block
#define NQT 14     // q tiles per (b,h)  (448/32)
#define KT 32      // k rows per staged tile
#define NKT 32     // 1024/KT

typedef short bf16x8 __attribute__((ext_vector_type(8)));
typedef float f32x4 __attribute__((ext_vector_type(4)));
typedef unsigned int u32;

static __device__ __forceinline__ unsigned short f2bf(float f) {
  union { float f; u32 u; } v; v.f = f;
  u32 u = v.u;
  return (unsigned short)((u + 0x7fffu + ((u >> 16) & 1u)) >> 16);
}

static __device__ __forceinline__ float dot4(float4 a, float4 b) {
  return a.x * b.x + a.y * b.y + a.z * b.z + a.w * b.w;
}

static __device__ __forceinline__ void load_lds16(const void* g, void* l) {
  __builtin_amdgcn_global_load_lds((const __attribute__((address_space(1))) u32*)g,
                                   (__attribute__((address_space(3))) u32*)l, 16, 0, 0);
}

// ---------------- Kernel A: f32 -> bf16 convert (W_in) ----------------
__global__ __launch_bounds__(256) void k_cvt(const float* __restrict__ in,
                                             unsigned short* __restrict__ out, int n4) {
  int i = blockIdx.x * 256 + threadIdx.x;
  if (i < n4) {
    float4 v = ((const float4*)in)[i];
    ushort4 o;
    o.x = f2bf(v.x); o.y = f2bf(v.y); o.z = f2bf(v.z); o.w = f2bf(v.w);
    ((ushort4*)out)[i] = o;
  }
}

// ---------------- Kernel P: split hidden -> bf16 hi plane + lo plane ----------------
__global__ __launch_bounds__(256) void k_pack(const float* __restrict__ hid,
                                              unsigned short* __restrict__ Phi,
                                              unsigned short* __restrict__ Plo) {
  int i = blockIdx.x * 256 + threadIdx.x;   // f32x4 index, total NB*SLEN*HID/4
  float4 x = ((const float4*)hid)[i];
  float e[4] = {x.x, x.y, x.z, x.w};
  ushort4 hv, lv;
  unsigned short* hp = (unsigned short*)&hv;
  unsigned short* lp = (unsigned short*)&lv;
#pragma unroll
  for (int j = 0; j < 4; ++j) {
    u32 u = __float_as_uint(e[j]);
    u32 hb = (u + 0x7fffu + ((u >> 16) & 1u)) >> 16;
    float r = e[j] - __uint_as_float(hb << 16);
    u32 ur = __float_as_uint(r);
    u32 lb = (ur + 0x7fffu + ((ur >> 16) & 1u)) >> 16;
    hp[j] = (unsigned short)hb;
    lp[j] = (unsigned short)lb;
  }
  ((ushort4*)Phi)[i] = hv;
  ((ushort4*)Plo)[i] = lv;
}

// ---------------- Kernel B: single-pass MFMA scores, S in registers ----------------
// grid = 896 (XCD-grouped). Block: one (b,h), 32 q rows, 4 waves:
// wq=wv&1 (16-row half), wk=wv>>1 (16-col half of each 32-col K tile).
// Each thread holds its 128 scores as exp() values in registers e[32][4]
// (fully unrolled -> static indices -> no scratch). Epilogue: z via shfl +
// zbuf, colsums via shfl into cs[2][1024], then combine.
__global__ __launch_bounds__(256) void k_scores(const unsigned short* __restrict__ Phi,
                                                const unsigned short* __restrict__ Plo,
                                                float* __restrict__ part) {
  __shared__ unsigned short Kh[2][KT * HD];   // 2 x 8 KB
  __shared__ unsigned short Kl[2][KT * HD];   // 2 x 8 KB
  __shared__ float cs[2][SLEN];               // 8 KB
  __shared__ float zbuf[2][QT];               // 256 B

  int bid = blockIdx.x;
  int xr = bid & 7, sl = bid >> 3;            // group same-bh blocks on one XCD
  int bh = xr * 8 + sl / NQT;
  int qt = sl % NQT;
  int b = bh >> 5, h = bh & 31;
  int t = threadIdx.x, l = t & 63, wv = t >> 6;
  int wq = wv & 1, wk = wv >> 1;

  const unsigned short* PhB = Phi + (size_t)b * SLEN * HID + h * HD;
  const unsigned short* PlB = Plo + (size_t)b * SLEN * HID + h * HD;

  // ---- Q fragments (registers, reused across all tiles) ----
  bf16x8 qhi[4], qlo[4];
  {
    int ql = qt * QT + wq * 16 + (l & 15);
    int qg = (ql < OFF) ? ql : ql + VT;
    const unsigned short* ph = PhB + (size_t)qg * HID + (l >> 4) * 8;
    const unsigned short* pl = PlB + (size_t)qg * HID + (l >> 4) * 8;
#pragma unroll
    for (int ds = 0; ds < 4; ++ds) {
      qhi[ds] = *(const bf16x8*)(ph + ds * 32);
      qlo[ds] = *(const bf16x8*)(pl + ds * 32);
    }
  }

  // staging: linear LDS dest (lane*16B), inverse-swizzled global source.
  int sg0 = (wv * 2 + 0) * 64 + l;
  int sg1 = (wv * 2 + 1) * 64 + l;
  int srow0 = sg0 >> 4, srow1 = sg1 >> 4;
  size_t soff0 = (size_t)srow0 * HID + ((sg0 & 15) ^ (srow0 & 7)) * 8;
  size_t soff1 = (size_t)srow1 * HID + ((sg1 & 15) ^ (srow1 & 7)) * 8;

#define STAGE(kt_, bb_)                                                        \
  do {                                                                         \
    size_t kb_ = (size_t)(kt_)*KT * HID;                                       \
    load_lds16(PhB + kb_ + soff0, &Kh[bb_][sg0 * 8]);                          \
    load_lds16(PlB + kb_ + soff0, &Kl[bb_][sg0 * 8]);                          \
    load_lds16(PhB + kb_ + soff1, &Kh[bb_][sg1 * 8]);                          \
    load_lds16(PlB + kb_ + soff1, &Kl[bb_][sg1 * 8]);                          \
  } while (0)

  const float scale = 0.088388347648318447f;  // 1/sqrt(128)

  // read-fragment offsets (XOR-swizzled): row = wk*16 + (l&15)
  int frow = wk * 16 + (l & 15);
  int foff[4];
#pragma unroll
  for (int ds = 0; ds < 4; ++ds)
    foff[ds] = frow * HD + (((ds * 4) + (l >> 4)) ^ (frow & 7)) * 8;

  float e[NKT][4];   // exp(score) — stays in registers (static indices only)

  STAGE(0, 0);
  __syncthreads();

#pragma unroll
  for (int tt = 0; tt < NKT; ++tt) {
    int bb = tt & 1;
    if (tt + 1 < NKT) STAGE(tt + 1, bb ^ 1);

    // 3 independent MFMA chains: hi*hi, hi*lo, lo*hi
    f32x4 aP = {0.f, 0.f, 0.f, 0.f};
    f32x4 aQ = {0.f, 0.f, 0.f, 0.f};
    f32x4 aR = {0.f, 0.f, 0.f, 0.f};
#pragma unroll
    for (int ds = 0; ds < 4; ++ds) {
      bf16x8 kh = *(const bf16x8*)&Kh[bb][foff[ds]];
      bf16x8 kl = *(const bf16x8*)&Kl[bb][foff[ds]];
      aP = __builtin_amdgcn_mfma_f32_16x16x32_bf16(qhi[ds], kh, aP, 0, 0, 0);
      aQ = __builtin_amdgcn_mfma_f32_16x16x32_bf16(qhi[ds], kl, aQ, 0, 0, 0);
      aR = __builtin_amdgcn_mfma_f32_16x16x32_bf16(qlo[ds], kh, aR, 0, 0, 0);
    }
#pragma unroll
    for (int j = 0; j < 4; ++j)
      e[tt][j] = __expf((aP[j] + aQ[j] + aR[j]) * scale);

    __syncthreads();
  }

  // ---- z per row: in-thread sum over tiles, shfl over the 16 k-lanes ----
  float zr[4] = {0.f, 0.f, 0.f, 0.f};
#pragma unroll
  for (int tt = 0; tt < NKT; ++tt)
#pragma unroll
    for (int j = 0; j < 4; ++j) zr[j] += e[tt][j];
#pragma unroll
  for (int j = 0; j < 4; ++j) {
    float z = zr[j];
    z += __shfl_xor(z, 1);
    z += __shfl_xor(z, 2);
    z += __shfl_xor(z, 4);
    z += __shfl_xor(z, 8);
    zr[j] = z;
  }
  if ((l & 15) == 0) {
#pragma unroll
    for (int j = 0; j < 4; ++j)
      zbuf[wk][wq * 16 + (l >> 4) * 4 + j] = zr[j];
  }
  __syncthreads();

  float zinv[4];
#pragma unroll
  for (int j = 0; j < 4; ++j) {
    int row = wq * 16 + (l >> 4) * 4 + j;
    zinv[j] = 1.f / (zbuf[0][row] + zbuf[1][row]);
  }

  // ---- colsums: per tile, weighted sum over the wave's 16 q rows ----
#pragma unroll
  for (int tt = 0; tt < NKT; ++tt) {
    float v = e[tt][0] * zinv[0] + e[tt][1] * zinv[1] +
              e[tt][2] * zinv[2] + e[tt][3] * zinv[3];
    v += __shfl_xor(v, 16);
    v += __shfl_xor(v, 32);
    if (l < 16) cs[wq][tt * KT + wk * 16 + l] = v;
  }
  __syncthreads();

  for (int c5 = t; c5 < VT; c5 += 256) {
    int col = OFF + c5;
    part[((size_t)bh * NQT + qt) * VT + c5] = cs[0][col] + cs[1][col];
  }
#undef STAGE
}

// ---------------- Kernel C: per-head softmax / pool / argmax / w ----------------
__global__ __launch_bounds__(256) void k_head(const float* __restrict__ part,
                                              float* __restrict__ params) {
  int bh = blockIdx.x;
  int t = threadIdx.x;
  __shared__ float ia[VT];
  __shared__ float sfe[VT];
  __shared__ float rbuf[256];
  __shared__ int ribuf[256];

  for (int i = t; i < VT; i += 256) {
    float s = 0.f;
    const float* p = part + (size_t)bh * NQT * VT + i;
    for (int c = 0; c < NQT; ++c) s += p[(size_t)c * VT];
    ia[i] = s;
  }
  __syncthreads();

  float lm = -1e30f;
  for (int i = t; i < VT; i += 256) lm = fmaxf(lm, ia[i]);
  rbuf[t] = lm;
  __syncthreads();
  for (int s = 128; s > 0; s >>= 1) {
    if (t < s) rbuf[t] = fmaxf(rbuf[t], rbuf[t + s]);
    __syncthreads();
  }
  float M = rbuf[0];
  __syncthreads();

  float lz = 0.f;
  for (int i = t; i < VT; i += 256) {
    float e = __expf(ia[i] - M);
    sfe[i] = e;
    lz += e;
  }
  rbuf[t] = lz;
  __syncthreads();
  for (int s = 128; s > 0; s >>= 1) {
    if (t < s) rbuf[t] += rbuf[t + s];
    __syncthreads();
  }
  float invZ = 1.f / rbuf[0];
  __syncthreads();

  float pv = -1e30f;
  int pidx = 0x7fffffff;
  if (t < PEW * PEW) {
    int r = t / PEW, c = t % PEW;
    float s = 0.f;
    for (int i = 0; i < KW; ++i)
      for (int j = 0; j < KW; ++j) s += ia[(r + i) * EDGE + (c + j)];
    pv = s;
    pidx = t;
  }
  rbuf[t] = pv;
  ribuf[t] = pidx;
  __syncthreads();
  for (int s = 128; s > 0; s >>= 1) {
    if (t < s) {
      float ov = rbuf[t + s];
      int oi = ribuf[t + s];
      if (ov > rbuf[t] || (ov == rbuf[t] && oi < ribuf[t])) {
        rbuf[t] = ov;
        ribuf[t] = oi;
      }
    }
    __syncthreads();
  }
  int idx = ribuf[0];
  int r0 = idx / PEW, c0 = idx % PEW;
  __syncthreads();

  float lw = 0.f;
  if (t < KW * KW) {
    int i = t / KW, j = t % KW;
    lw = sfe[(r0 + i) * EDGE + (c0 + j)];
  }
  rbuf[t] = lw;
  __syncthreads();
  for (int s = 128; s > 0; s >>= 1) {
    if (t < s) rbuf[t] += rbuf[t + s];
    __syncthreads();
  }
  if (t == 0) {
    params[bh * 4 + 0] = rbuf[0] * invZ;
    ((int*)params)[bh * 4 + 1] = r0;
    ((int*)params)[bh * 4 + 2] = c0;
  }
}

// ---------------- Kernel D2: per-head window up-projection -> bf16 into Phi ----------------
__global__ __launch_bounds__(256) void k_img(const float* __restrict__ hid,
                                             const float* __restrict__ Wup,
                                             const float* __restrict__ params,
                                             unsigned short* __restrict__ hs) {
  int bid = blockIdx.x;
  int g = bid & 3;
  int bh = bid >> 2;
  int b = bh / NH, h = bh % NH;
  float w = params[bh * 4];
  int r0 = ((const int*)params)[bh * 4 + 1];
  int c0 = ((const int*)params)[bh * 4 + 2];
  int t = threadIdx.x;

  __shared__ float win[36][HD];
  for (int idx = t; idx < 36 * (HD / 4); idx += 256) {
    int cell = idx >> 5;
    int c4 = idx & 31;
    int cc = g * 36 + cell;
    int i = cc / 12, j = cc % 12;
    int s = OFF + (r0 + i) * EDGE + (c0 + j);
    *(float4*)&win[cell][c4 * 4] =
        *(const float4*)(hid + ((size_t)(b * SLEN + s)) * HID + h * HD + c4 * 4);
  }
  __syncthreads();

  float acc0[36], acc1[36];
#pragma unroll
  for (int cell = 0; cell < 36; ++cell) { acc0[cell] = 0.f; acc1[cell] = 0.f; }

  int e0 = t, e1 = t + 256;
  const float* w0 = Wup + (size_t)e0 * HD;
  const float* w1 = Wup + (size_t)e1 * HD;
  for (int c = 0; c < 32; ++c) {
    float4 u0 = *(const float4*)(w0 + c * 4);
    float4 u1 = *(const float4*)(w1 + c * 4);
#pragma unroll
    for (int cell = 0; cell < 36; ++cell) {
      float4 qv = *(const float4*)&win[cell][c * 4];
      acc0[cell] += dot4(qv, u0);
      acc1[cell] += dot4(qv, u1);
    }
  }

  int si0 = e0 >> 8, sj0 = (e0 >> 7) & 1, d0 = e0 & 127;
  int si1 = e1 >> 8, sj1 = (e1 >> 7) & 1, d1 = e1 & 127;
#pragma unroll
  for (int cell = 0; cell < 36; ++cell) {
    int cc = g * 36 + cell;
    int i = cc / 12, j = cc % 12;
    {
      int srow = OFF + (2 * i + si0) * EDGE + (2 * j + sj0);
      hs[((size_t)(b * SLEN + srow)) * HID + h * HD + d0] = f2bf(acc0[cell] * w);
    }
    {
      int srow = OFF + (2 * i + si1) * EDGE + (2 * j + sj1);
      hs[((size_t)(b * SLEN + srow)) * HID + h * HD + d1] = f2bf(acc1[cell] * w);
    }
  }
}

// ---------------- Kernel E: bf16 MFMA GEMM, silu + residual epilogue ----------------
__global__ __launch_bounds__(256) void k_gemm(const unsigned short* __restrict__ A,
                                              const unsigned short* __restrict__ Bm,
                                              const float* __restrict__ resid,
                                              float* __restrict__ out) {
  // bijective XCD swizzle: 512 wg, XCD x serves n-tile group [4x,4x+4) ->
  // 4 MB B-slice per XCD L2.
  int bid0 = blockIdx.x;
  int bid = (bid0 & 7) * 64 + (bid0 >> 3);
  int bm0 = (bid & 15) << 7;
  int bn0 = (bid >> 4) << 7;
  int t = threadIdx.x;
  int ln = t & 63, wv = t >> 6;
  int wr = wv >> 1, wc = wv & 1;

  __shared__ unsigned short lA[128 * 64];
  __shared__ unsigned short lB[128 * 64];

  f32x4 acc[4][4];
#pragma unroll
  for (int mi = 0; mi < 4; ++mi)
#pragma unroll
    for (int ni = 0; ni < 4; ++ni) acc[mi][ni] = (f32x4){0.f, 0.f, 0.f, 0.f};

  const unsigned short* aptr = A + (size_t)(bm0 + (t >> 3)) * HID + (t & 7) * 8;
  const unsigned short* bptr = Bm + (size_t)(bn0 + (t >> 3)) * HID + (t & 7) * 8;
  unsigned short* la = &lA[t * 8];
  unsigned short* lb = &lB[t * 8];

  int arow_a = (wr * 64 + (ln & 15)) * 64 + (ln >> 4) * 8;
  int arow_b = (wc * 64 + (ln & 15)) * 64 + (ln >> 4) * 8;

  for (int k0 = 0; k0 < HID; k0 += 64) {
#pragma unroll
    for (int i = 0; i < 4; ++i)
      load_lds16(aptr + (size_t)i * 32 * HID + k0, la + i * 2048);
#pragma unroll
    for (int i = 0; i < 4; ++i)
      load_lds16(bptr + (size_t)i * 32 * HID + k0, lb + i * 2048);
    __syncthreads();
#pragma unroll
    for (int ks = 0; ks < 2; ++ks) {
      bf16x8 aF[4], bF[4];
#pragma unroll
      for (int mi = 0; mi < 4; ++mi)
        aF[mi] = *(const bf16x8*)&lA[arow_a + mi * 16 * 64 + ks * 32];
#pragma unroll
      for (int ni = 0; ni < 4; ++ni)
        bF[ni] = *(const bf16x8*)&lB[arow_b + ni * 16 * 64 + ks * 32];
#pragma unroll
      for (int mi = 0; mi < 4; ++mi)
#pragma unroll
        for (int ni = 0; ni < 4; ++ni)
          acc[mi][ni] = __builtin_amdgcn_mfma_f32_16x16x32_bf16(aF[mi], bF[ni],
                                                                acc[mi][ni], 0, 0, 0);
    }
    __syncthreads();
  }

#pragma unroll
  for (int mi = 0; mi < 4; ++mi) {
#pragma unroll
    for (int ni = 0; ni < 4; ++ni) {
      int m = bm0 + wr * 64 + mi * 16 + (ln >> 4) * 4;
      int n = bn0 + wc * 64 + ni * 16 + (ln & 15);
#pragma unroll
      for (int r = 0; r < 4; ++r) {
        float x = acc[mi][ni][r];
        float s = x / (1.f + __expf(-x));
        size_t o = (size_t)(m + r) * HID + n;
        out[o] = resid[o] + s;
      }
    }
  }
}

extern "C" void kernel_launch(void* const* d_in, const int* in_sizes, int n_in,
                              void* d_out, int out_size, void* d_ws, size_t ws_size,
                              hipStream_t stream) {
  const float* hid = (const float*)d_in[0];
  const float* Win = (const float*)d_in[1];
  const float* Wup = (const float*)d_in[2];
  float* out = (float*)d_out;
  char* ws = (char*)d_ws;

  unsigned short* Wb  = (unsigned short*)ws;                 // 33,554,432 B
  unsigned short* Phi = (unsigned short*)(ws + 33554432);    // 16,777,216 B
  float* part = (float*)(ws + 50331648);                     //  2,064,384 B
  float* params = (float*)(ws + 52396032);                   //      1,024 B
  unsigned short* Plo = (unsigned short*)d_out;  // lo plane lives in d_out until k_gemm

  k_cvt<<<16384, 256, 0, stream>>>(Win, Wb, HID * HID / 4);
  k_pack<<<NB * SLEN * HID / 4 / 256, 256, 0, stream>>>(hid, Phi, Plo);
  k_scores<<<NB * NH * NQT, 256, 0, stream>>>(Phi, Plo, part);
  k_head<<<NB * NH, 256, 0, stream>>>(part, params);
  k_img<<<NB * NH * 4, 256, 0, stream>>>(hid, Wup, params, Phi);
  k_gemm<<<512, 256, 0, stream>>>(Phi, Wb, hid, out);
}

// Round 5
// 242.325 us; speedup vs baseline: 1.8208x; 1.0179x over previous
//
#include <hip/hip_runtime.h>
#include <hip/hip_bf16.h>
#include <math.h>

#define HID 4096
#define NH 32
#define HD 128
#define EDGE 24
#define KW 12
#define PEW 13
#define VT 576
#define OFF 5
#define NB 2
#define SLEN 1024
#define QT 32      // q rows per scores block
#define NQT 14     // q tiles per (b,h)  (448/32)
#define KT 32      // k rows per staged tile
#define NKT 32     // 1024/KT

typedef short bf16x8 __attribute__((ext_vector_type(8)));
typedef float f32x4 __attribute__((ext_vector_type(4)));
typedef unsigned int u32;

static __device__ __forceinline__ unsigned short f2bf(float f) {
  union { float f; u32 u; } v; v.f = f;
  u32 u = v.u;
  return (unsigned short)((u + 0x7fffu + ((u >> 16) & 1u)) >> 16);
}

static __device__ __forceinline__ float dot4(float4 a, float4 b) {
  return a.x * b.x + a.y * b.y + a.z * b.z + a.w * b.w;
}

static __device__ __forceinline__ void load_lds16(const void* g, void* l) {
  __builtin_amdgcn_global_load_lds((const __attribute__((address_space(1))) u32*)g,
                                   (__attribute__((address_space(3))) u32*)l, 16, 0, 0);
}

// ---------------- Kernel A: f32 -> bf16 convert (W_in) ----------------
__global__ __launch_bounds__(256) void k_cvt(const float* __restrict__ in,
                                             unsigned short* __restrict__ out, int n4) {
  int i = blockIdx.x * 256 + threadIdx.x;
  if (i < n4) {
    float4 v = ((const float4*)in)[i];
    ushort4 o;
    o.x = f2bf(v.x); o.y = f2bf(v.y); o.z = f2bf(v.z); o.w = f2bf(v.w);
    ((ushort4*)out)[i] = o;
  }
}

// ---------------- Kernel P: split hidden -> bf16 hi plane + lo plane ----------------
__global__ __launch_bounds__(256) void k_pack(const float* __restrict__ hid,
                                              unsigned short* __restrict__ Phi,
                                              unsigned short* __restrict__ Plo) {
  int i = blockIdx.x * 256 + threadIdx.x;   // f32x4 index, total NB*SLEN*HID/4
  float4 x = ((const float4*)hid)[i];
  float e[4] = {x.x, x.y, x.z, x.w};
  ushort4 hv, lv;
  unsigned short* hp = (unsigned short*)&hv;
  unsigned short* lp = (unsigned short*)&lv;
#pragma unroll
  for (int j = 0; j < 4; ++j) {
    u32 u = __float_as_uint(e[j]);
    u32 hb = (u + 0x7fffu + ((u >> 16) & 1u)) >> 16;
    float r = e[j] - __uint_as_float(hb << 16);
    u32 ur = __float_as_uint(r);
    u32 lb = (ur + 0x7fffu + ((ur >> 16) & 1u)) >> 16;
    hp[j] = (unsigned short)hb;
    lp[j] = (unsigned short)lb;
  }
  ((ushort4*)Phi)[i] = hv;
  ((ushort4*)Plo)[i] = lv;
}

// ---------------- Kernel B: single-pass MFMA scores, S in registers ----------------
__global__ __launch_bounds__(256) void k_scores(const unsigned short* __restrict__ Phi,
                                                const unsigned short* __restrict__ Plo,
                                                float* __restrict__ part) {
  __shared__ unsigned short Kh[2][KT * HD];   // 2 x 8 KB
  __shared__ unsigned short Kl[2][KT * HD];   // 2 x 8 KB
  __shared__ float cs[2][SLEN];               // 8 KB
  __shared__ float zbuf[2][QT];               // 256 B

  int bid = blockIdx.x;
  int xr = bid & 7, sl = bid >> 3;            // group same-bh blocks on one XCD
  int bh = xr * 8 + sl / NQT;
  int qt = sl % NQT;
  int b = bh >> 5, h = bh & 31;
  int t = threadIdx.x, l = t & 63, wv = t >> 6;
  int wq = wv & 1, wk = wv >> 1;

  const unsigned short* PhB = Phi + (size_t)b * SLEN * HID + h * HD;
  const unsigned short* PlB = Plo + (size_t)b * SLEN * HID + h * HD;

  bf16x8 qhi[4], qlo[4];
  {
    int ql = qt * QT + wq * 16 + (l & 15);
    int qg = (ql < OFF) ? ql : ql + VT;
    const unsigned short* ph = PhB + (size_t)qg * HID + (l >> 4) * 8;
    const unsigned short* pl = PlB + (size_t)qg * HID + (l >> 4) * 8;
#pragma unroll
    for (int ds = 0; ds < 4; ++ds) {
      qhi[ds] = *(const bf16x8*)(ph + ds * 32);
      qlo[ds] = *(const bf16x8*)(pl + ds * 32);
    }
  }

  int sg0 = (wv * 2 + 0) * 64 + l;
  int sg1 = (wv * 2 + 1) * 64 + l;
  int srow0 = sg0 >> 4, srow1 = sg1 >> 4;
  size_t soff0 = (size_t)srow0 * HID + ((sg0 & 15) ^ (srow0 & 7)) * 8;
  size_t soff1 = (size_t)srow1 * HID + ((sg1 & 15) ^ (srow1 & 7)) * 8;

#define STAGE(kt_, bb_)                                                        \
  do {                                                                         \
    size_t kb_ = (size_t)(kt_)*KT * HID;                                       \
    load_lds16(PhB + kb_ + soff0, &Kh[bb_][sg0 * 8]);                          \
    load_lds16(PlB + kb_ + soff0, &Kl[bb_][sg0 * 8]);                          \
    load_lds16(PhB + kb_ + soff1, &Kh[bb_][sg1 * 8]);                          \
    load_lds16(PlB + kb_ + soff1, &Kl[bb_][sg1 * 8]);                          \
  } while (0)

  const float scale = 0.088388347648318447f;  // 1/sqrt(128)

  int frow = wk * 16 + (l & 15);
  int foff[4];
#pragma unroll
  for (int ds = 0; ds < 4; ++ds)
    foff[ds] = frow * HD + (((ds * 4) + (l >> 4)) ^ (frow & 7)) * 8;

  float e[NKT][4];

  STAGE(0, 0);
  __syncthreads();

#pragma unroll
  for (int tt = 0; tt < NKT; ++tt) {
    int bb = tt & 1;
    if (tt + 1 < NKT) STAGE(tt + 1, bb ^ 1);

    f32x4 aP = {0.f, 0.f, 0.f, 0.f};
    f32x4 aQ = {0.f, 0.f, 0.f, 0.f};
    f32x4 aR = {0.f, 0.f, 0.f, 0.f};
#pragma unroll
    for (int ds = 0; ds < 4; ++ds) {
      bf16x8 kh = *(const bf16x8*)&Kh[bb][foff[ds]];
      bf16x8 kl = *(const bf16x8*)&Kl[bb][foff[ds]];
      aP = __builtin_amdgcn_mfma_f32_16x16x32_bf16(qhi[ds], kh, aP, 0, 0, 0);
      aQ = __builtin_amdgcn_mfma_f32_16x16x32_bf16(qhi[ds], kl, aQ, 0, 0, 0);
      aR = __builtin_amdgcn_mfma_f32_16x16x32_bf16(qlo[ds], kh, aR, 0, 0, 0);
    }
#pragma unroll
    for (int j = 0; j < 4; ++j)
      e[tt][j] = __expf((aP[j] + aQ[j] + aR[j]) * scale);

    __syncthreads();
  }

  float zr[4] = {0.f, 0.f, 0.f, 0.f};
#pragma unroll
  for (int tt = 0; tt < NKT; ++tt)
#pragma unroll
    for (int j = 0; j < 4; ++j) zr[j] += e[tt][j];
#pragma unroll
  for (int j = 0; j < 4; ++j) {
    float z = zr[j];
    z += __shfl_xor(z, 1);
    z += __shfl_xor(z, 2);
    z += __shfl_xor(z, 4);
    z += __shfl_xor(z, 8);
    zr[j] = z;
  }
  if ((l & 15) == 0) {
#pragma unroll
    for (int j = 0; j < 4; ++j)
      zbuf[wk][wq * 16 + (l >> 4) * 4 + j] = zr[j];
  }
  __syncthreads();

  float zinv[4];
#pragma unroll
  for (int j = 0; j < 4; ++j) {
    int row = wq * 16 + (l >> 4) * 4 + j;
    zinv[j] = 1.f / (zbuf[0][row] + zbuf[1][row]);
  }

#pragma unroll
  for (int tt = 0; tt < NKT; ++tt) {
    float v = e[tt][0] * zinv[0] + e[tt][1] * zinv[1] +
              e[tt][2] * zinv[2] + e[tt][3] * zinv[3];
    v += __shfl_xor(v, 16);
    v += __shfl_xor(v, 32);
    if (l < 16) cs[wq][tt * KT + wk * 16 + l] = v;
  }
  __syncthreads();

  for (int c5 = t; c5 < VT; c5 += 256) {
    int col = OFF + c5;
    part[((size_t)bh * NQT + qt) * VT + c5] = cs[0][col] + cs[1][col];
  }
#undef STAGE
}

// ---------------- Kernel C: per-head softmax / pool / argmax / w ----------------
__global__ __launch_bounds__(256) void k_head(const float* __restrict__ part,
                                              float* __restrict__ params) {
  int bh = blockIdx.x;
  int t = threadIdx.x;
  __shared__ float ia[VT];
  __shared__ float sfe[VT];
  __shared__ float rbuf[256];
  __shared__ int ribuf[256];

  for (int i = t; i < VT; i += 256) {
    float s = 0.f;
    const float* p = part + (size_t)bh * NQT * VT + i;
    for (int c = 0; c < NQT; ++c) s += p[(size_t)c * VT];
    ia[i] = s;
  }
  __syncthreads();

  float lm = -1e30f;
  for (int i = t; i < VT; i += 256) lm = fmaxf(lm, ia[i]);
  rbuf[t] = lm;
  __syncthreads();
  for (int s = 128; s > 0; s >>= 1) {
    if (t < s) rbuf[t] = fmaxf(rbuf[t], rbuf[t + s]);
    __syncthreads();
  }
  float M = rbuf[0];
  __syncthreads();

  float lz = 0.f;
  for (int i = t; i < VT; i += 256) {
    float e = __expf(ia[i] - M);
    sfe[i] = e;
    lz += e;
  }
  rbuf[t] = lz;
  __syncthreads();
  for (int s = 128; s > 0; s >>= 1) {
    if (t < s) rbuf[t] += rbuf[t + s];
    __syncthreads();
  }
  float invZ = 1.f / rbuf[0];
  __syncthreads();

  float pv = -1e30f;
  int pidx = 0x7fffffff;
  if (t < PEW * PEW) {
    int r = t / PEW, c = t % PEW;
    float s = 0.f;
    for (int i = 0; i < KW; ++i)
      for (int j = 0; j < KW; ++j) s += ia[(r + i) * EDGE + (c + j)];
    pv = s;
    pidx = t;
  }
  rbuf[t] = pv;
  ribuf[t] = pidx;
  __syncthreads();
  for (int s = 128; s > 0; s >>= 1) {
    if (t < s) {
      float ov = rbuf[t + s];
      int oi = ribuf[t + s];
      if (ov > rbuf[t] || (ov == rbuf[t] && oi < ribuf[t])) {
        rbuf[t] = ov;
        ribuf[t] = oi;
      }
    }
    __syncthreads();
  }
  int idx = ribuf[0];
  int r0 = idx / PEW, c0 = idx % PEW;
  __syncthreads();

  float lw = 0.f;
  if (t < KW * KW) {
    int i = t / KW, j = t % KW;
    lw = sfe[(r0 + i) * EDGE + (c0 + j)];
  }
  rbuf[t] = lw;
  __syncthreads();
  for (int s = 128; s > 0; s >>= 1) {
    if (t < s) rbuf[t] += rbuf[t + s];
    __syncthreads();
  }
  if (t == 0) {
    params[bh * 4 + 0] = rbuf[0] * invZ;
    ((int*)params)[bh * 4 + 1] = r0;
    ((int*)params)[bh * 4 + 2] = c0;
  }
}

// ---------------- Kernel D2: per-head window up-projection -> bf16 into Phi ----------------
__global__ __launch_bounds__(256) void k_img(const float* __restrict__ hid,
                                             const float* __restrict__ Wup,
                                             const float* __restrict__ params,
                                             unsigned short* __restrict__ hs) {
  int bid = blockIdx.x;
  int g = bid & 3;
  int bh = bid >> 2;
  int b = bh / NH, h = bh % NH;
  float w = params[bh * 4];
  int r0 = ((const int*)params)[bh * 4 + 1];
  int c0 = ((const int*)params)[bh * 4 + 2];
  int t = threadIdx.x;

  __shared__ float win[36][HD];
  for (int idx = t; idx < 36 * (HD / 4); idx += 256) {
    int cell = idx >> 5;
    int c4 = idx & 31;
    int cc = g * 36 + cell;
    int i = cc / 12, j = cc % 12;
    int s = OFF + (r0 + i) * EDGE + (c0 + j);
    *(float4*)&win[cell][c4 * 4] =
        *(const float4*)(hid + ((size_t)(b * SLEN + s)) * HID + h * HD + c4 * 4);
  }
  __syncthreads();

  float acc0[36], acc1[36];
#pragma unroll
  for (int cell = 0; cell < 36; ++cell) { acc0[cell] = 0.f; acc1[cell] = 0.f; }

  int e0 = t, e1 = t + 256;
  const float* w0 = Wup + (size_t)e0 * HD;
  const float* w1 = Wup + (size_t)e1 * HD;
  for (int c = 0; c < 32; ++c) {
    float4 u0 = *(const float4*)(w0 + c * 4);
    float4 u1 = *(const float4*)(w1 + c * 4);
#pragma unroll
    for (int cell = 0; cell < 36; ++cell) {
      float4 qv = *(const float4*)&win[cell][c * 4];
      acc0[cell] += dot4(qv, u0);
      acc1[cell] += dot4(qv, u1);
    }
  }

  int si0 = e0 >> 8, sj0 = (e0 >> 7) & 1, d0 = e0 & 127;
  int si1 = e1 >> 8, sj1 = (e1 >> 7) & 1, d1 = e1 & 127;
#pragma unroll
  for (int cell = 0; cell < 36; ++cell) {
    int cc = g * 36 + cell;
    int i = cc / 12, j = cc % 12;
    {
      int srow = OFF + (2 * i + si0) * EDGE + (2 * j + sj0);
      hs[((size_t)(b * SLEN + srow)) * HID + h * HD + d0] = f2bf(acc0[cell] * w);
    }
    {
      int srow = OFF + (2 * i + si1) * EDGE + (2 * j + sj1);
      hs[((size_t)(b * SLEN + srow)) * HID + h * HD + d1] = f2bf(acc1[cell] * w);
    }
  }
}

// ---------------- Kernel E: 8-phase counted-vmcnt bf16 MFMA GEMM ----------------
// C[m,e] = resid[m,e] + silu( sum_d A[m,d] * W[e,d] ),  M=2048, N=K=4096.
// BM=128, BN=256, BK=64; 256 blocks (1/CU), 512 threads (8 waves, 2Mx4N).
// Triple-buffered LDS (depth-2 prefetch) -> steady-state wait is vmcnt(6).
// T2 XOR-swizzle on both tiles: linear LDS dest + inverse-swizzled global src.
__global__ __launch_bounds__(512, 2) void k_gemm(const unsigned short* __restrict__ A,
                                                 const unsigned short* __restrict__ Bm,
                                                 const float* __restrict__ resid,
                                                 float* __restrict__ out) {
  __shared__ unsigned short lA[3][128 * 64];   // 48 KB
  __shared__ unsigned short lB[3][256 * 64];   // 96 KB

  int bid0 = blockIdx.x;
  int swz = (bid0 & 7) * 32 + (bid0 >> 3);     // XCD-contiguous (256 % 8 == 0)
  int bm0 = (swz & 15) << 7;
  int bn0 = (swz >> 4) << 8;                   // each XCD: 512-col B slice = 4 MB L2
  int t = threadIdx.x;
  int ln = t & 63, wv = t >> 6;
  int wr = wv >> 2, wc = wv & 3;               // 2 x 4 wave grid, 64x64 C per wave

  // fragment read offsets (XOR-swizzled 16B granules; 2-way max conflict)
  int aOff[4][2], bOff[4][2];
#pragma unroll
  for (int q = 0; q < 4; ++q)
#pragma unroll
    for (int ks = 0; ks < 2; ++ks) {
      int ga = ks * 4 + (ln >> 4);
      int ra = wr * 64 + q * 16 + (ln & 15);
      aOff[q][ks] = ra * 64 + ((ga ^ (ra & 7)) * 8);
      int rb = wc * 64 + q * 16 + (ln & 15);
      bOff[q][ks] = rb * 64 + ((ga ^ (rb & 7)) * 8);
    }

  // staging: linear LDS dest granules, inverse-swizzled global source cols
  const unsigned short* aS0; const unsigned short* aS1;
  unsigned short *aD0, *aD1;
  {
    int G = t, r = G >> 3, g = G & 7;
    aS0 = A + (size_t)(bm0 + r) * HID + ((g ^ (r & 7)) * 8);
    aD0 = &lA[0][0] + G * 8;
    G = t + 512; r = G >> 3; g = G & 7;
    aS1 = A + (size_t)(bm0 + r) * HID + ((g ^ (r & 7)) * 8);
    aD1 = &lA[0][0] + G * 8;
  }
  const unsigned short *bS0, *bS1, *bS2, *bS3;
  unsigned short *bD0, *bD1, *bD2, *bD3;
  {
    int G = t, r = G >> 3, g = G & 7;
    bS0 = Bm + (size_t)(bn0 + r) * HID + ((g ^ (r & 7)) * 8);
    bD0 = &lB[0][0] + G * 8;
    G = t + 512; r = G >> 3; g = G & 7;
    bS1 = Bm + (size_t)(bn0 + r) * HID + ((g ^ (r & 7)) * 8);
    bD1 = &lB[0][0] + G * 8;
    G = t + 1024; r = G >> 3; g = G & 7;
    bS2 = Bm + (size_t)(bn0 + r) * HID + ((g ^ (r & 7)) * 8);
    bD2 = &lB[0][0] + G * 8;
    G = t + 1536; r = G >> 3; g = G & 7;
    bS3 = Bm + (size_t)(bn0 + r) * HID + ((g ^ (r & 7)) * 8);
    bD3 = &lB[0][0] + G * 8;
  }

#define STAGE_A(kt_, nb_)                                  \
  load_lds16(aS0 + (kt_) * 64, aD0 + (nb_) * 8192);        \
  load_lds16(aS1 + (kt_) * 64, aD1 + (nb_) * 8192);
#define STAGE_B01(kt_, nb_)                                \
  load_lds16(bS0 + (kt_) * 64, bD0 + (nb_) * 16384);       \
  load_lds16(bS1 + (kt_) * 64, bD1 + (nb_) * 16384);
#define STAGE_B23(kt_, nb_)                                \
  load_lds16(bS2 + (kt_) * 64, bD2 + (nb_) * 16384);       \
  load_lds16(bS3 + (kt_) * 64, bD3 + (nb_) * 16384);

  f32x4 acc[4][4];
#pragma unroll
  for (int mi = 0; mi < 4; ++mi)
#pragma unroll
    for (int ni = 0; ni < 4; ++ni) acc[mi][ni] = (f32x4){0.f, 0.f, 0.f, 0.f};

  // prologue: stage tiles 0 and 1 (6 loads each)
  STAGE_A(0, 0); STAGE_B01(0, 0); STAGE_B23(0, 0);
  STAGE_A(1, 1); STAGE_B01(1, 1); STAGE_B23(1, 1);
  asm volatile("s_waitcnt vmcnt(6)" ::: "memory");   // tile 0 landed
  __builtin_amdgcn_s_barrier();

#define MFMA8(NI, B0_, B1_)                                                       \
  __builtin_amdgcn_s_setprio(1);                                                  \
  acc[0][NI] = __builtin_amdgcn_mfma_f32_16x16x32_bf16(aF00, B0_, acc[0][NI], 0, 0, 0); \
  acc[0][NI] = __builtin_amdgcn_mfma_f32_16x16x32_bf16(aF01, B1_, acc[0][NI], 0, 0, 0); \
  acc[1][NI] = __builtin_amdgcn_mfma_f32_16x16x32_bf16(aF10, B0_, acc[1][NI], 0, 0, 0); \
  acc[1][NI] = __builtin_amdgcn_mfma_f32_16x16x32_bf16(aF11, B1_, acc[1][NI], 0, 0, 0); \
  acc[2][NI] = __builtin_amdgcn_mfma_f32_16x16x32_bf16(aF20, B0_, acc[2][NI], 0, 0, 0); \
  acc[2][NI] = __builtin_amdgcn_mfma_f32_16x16x32_bf16(aF21, B1_, acc[2][NI], 0, 0, 0); \
  acc[3][NI] = __builtin_amdgcn_mfma_f32_16x16x32_bf16(aF30, B0_, acc[3][NI], 0, 0, 0); \
  acc[3][NI] = __builtin_amdgcn_mfma_f32_16x16x32_bf16(aF31, B1_, acc[3][NI], 0, 0, 0); \
  __builtin_amdgcn_s_setprio(0);

#define WAIT_LGKM()                                        \
  asm volatile("s_waitcnt lgkmcnt(0)" ::: "memory");       \
  __builtin_amdgcn_sched_barrier(0);

  int cur = 0;
  for (int kt = 0; kt < 64; ++kt) {
    int nb = cur + 2; if (nb >= 3) nb -= 3;    // (kt+2)%3
    const unsigned short* Ab = &lA[0][0] + cur * 8192;
    const unsigned short* Bb = &lB[0][0] + cur * 16384;
    const int kt2 = kt + 2;
    const bool st = (kt < 62);

    // ---- phase 0: all A frags + B ni=0; stage A of kt+2 ----
    bf16x8 aF00 = *(const bf16x8*)(Ab + aOff[0][0]);
    bf16x8 aF01 = *(const bf16x8*)(Ab + aOff[0][1]);
    bf16x8 aF10 = *(const bf16x8*)(Ab + aOff[1][0]);
    bf16x8 aF11 = *(const bf16x8*)(Ab + aOff[1][1]);
    bf16x8 aF20 = *(const bf16x8*)(Ab + aOff[2][0]);
    bf16x8 aF21 = *(const bf16x8*)(Ab + aOff[2][1]);
    bf16x8 aF30 = *(const bf16x8*)(Ab + aOff[3][0]);
    bf16x8 aF31 = *(const bf16x8*)(Ab + aOff[3][1]);
    {
      bf16x8 b0 = *(const bf16x8*)(Bb + bOff[0][0]);
      bf16x8 b1 = *(const bf16x8*)(Bb + bOff[0][1]);
      if (st) { STAGE_A(kt2, nb); }
      __builtin_amdgcn_s_barrier();
      WAIT_LGKM();
      MFMA8(0, b0, b1);
      __builtin_amdgcn_s_barrier();
    }
    // ---- phase 1: B ni=1; stage B01 ----
    {
      bf16x8 b0 = *(const bf16x8*)(Bb + bOff[1][0]);
      bf16x8 b1 = *(const bf16x8*)(Bb + bOff[1][1]);
      if (st) { STAGE_B01(kt2, nb); }
      __builtin_amdgcn_s_barrier();
      WAIT_LGKM();
      MFMA8(1, b0, b1);
      __builtin_amdgcn_s_barrier();
    }
    // ---- phase 2: B ni=2; stage B23 ----
    {
      bf16x8 b0 = *(const bf16x8*)(Bb + bOff[2][0]);
      bf16x8 b1 = *(const bf16x8*)(Bb + bOff[2][1]);
      if (st) { STAGE_B23(kt2, nb); }
      __builtin_amdgcn_s_barrier();
      WAIT_LGKM();
      MFMA8(2, b0, b1);
      __builtin_amdgcn_s_barrier();
    }
    // ---- phase 3: B ni=3; counted vmcnt + rotate ----
    {
      bf16x8 b0 = *(const bf16x8*)(Bb + bOff[3][0]);
      bf16x8 b1 = *(const bf16x8*)(Bb + bOff[3][1]);
      __builtin_amdgcn_s_barrier();
      WAIT_LGKM();
      MFMA8(3, b0, b1);
      if (kt < 62) {
        asm volatile("s_waitcnt vmcnt(6)" ::: "memory");   // tile kt+1 landed
      } else if (kt == 62) {
        asm volatile("s_waitcnt vmcnt(0)" ::: "memory");   // tile 63 landed
      }
      __builtin_amdgcn_s_barrier();
    }
    cur = cur + 1; if (cur >= 3) cur = 0;
  }
#undef STAGE_A
#undef STAGE_B01
#undef STAGE_B23
#undef MFMA8
#undef WAIT_LGKM

  // epilogue: silu + residual, f32 out
#pragma unroll
  for (int mi = 0; mi < 4; ++mi) {
#pragma unroll
    for (int ni = 0; ni < 4; ++ni) {
      int m = bm0 + wr * 64 + mi * 16 + (ln >> 4) * 4;
      int n = bn0 + wc * 64 + ni * 16 + (ln & 15);
#pragma unroll
      for (int r = 0; r < 4; ++r) {
        float x = acc[mi][ni][r];
        float s = x / (1.f + __expf(-x));
        size_t o = (size_t)(m + r) * HID + n;
        out[o] = resid[o] + s;
      }
    }
  }
}

extern "C" void kernel_launch(void* const* d_in, const int* in_sizes, int n_in,
                              void* d_out, int out_size, void* d_ws, size_t ws_size,
                              hipStream_t stream) {
  const float* hid = (const float*)d_in[0];
  const float* Win = (const float*)d_in[1];
  const float* Wup = (const float*)d_in[2];
  float* out = (float*)d_out;
  char* ws = (char*)d_ws;

  unsigned short* Wb  = (unsigned short*)ws;                 // 33,554,432 B
  unsigned short* Phi = (unsigned short*)(ws + 33554432);    // 16,777,216 B
  float* part = (float*)(ws + 50331648);                     //  2,064,384 B
  float* params = (float*)(ws + 52396032);                   //      1,024 B
  unsigned short* Plo = (unsigned short*)d_out;  // lo plane lives in d_out until k_gemm

  k_cvt<<<16384, 256, 0, stream>>>(Win, Wb, HID * HID / 4);
  k_pack<<<NB * SLEN * HID / 4 / 256, 256, 0, stream>>>(hid, Phi, Plo);
  k_scores<<<NB * NH * NQT, 256, 0, stream>>>(Phi, Plo, part);
  k_head<<<NB * NH, 256, 0, stream>>>(part, params);
  k_img<<<NB * NH * 4, 256, 0, stream>>>(hid, Wup, params, Phi);
  k_gemm<<<256, 512, 0, stream>>>(Phi, Wb, hid, out);
}

// Round 6
// 218.339 us; speedup vs baseline: 2.0209x; 1.1099x over previous
//
#include <hip/hip_runtime.h>
#include <hip/hip_bf16.h>
#include <math.h>

#define HID 4096
#define NH 32
#define HD 128
#define EDGE 24
#define KW 12
#define PEW 13
#define VT 576
#define OFF 5
#define NB 2
#define SLEN 1024
#define QT 32      // q rows per scores unit
#define NQT 14     // q tiles per (b,h)  (448/32)
#define KT 32      // k rows per staged tile
#define NKT 32     // 1024/KT

typedef short bf16x8 __attribute__((ext_vector_type(8)));
typedef float f32x4 __attribute__((ext_vector_type(4)));
typedef unsigned int u32;

static __device__ __forceinline__ unsigned short f2bf(float f) {
  union { float f; u32 u; } v; v.f = f;
  u32 u = v.u;
  return (unsigned short)((u + 0x7fffu + ((u >> 16) & 1u)) >> 16);
}

static __device__ __forceinline__ float dot4(float4 a, float4 b) {
  return a.x * b.x + a.y * b.y + a.z * b.z + a.w * b.w;
}

static __device__ __forceinline__ void load_lds16(const void* g, void* l) {
  __builtin_amdgcn_global_load_lds((const __attribute__((address_space(1))) u32*)g,
                                   (__attribute__((address_space(3))) u32*)l, 16, 0, 0);
}

// ---------------- Kernel A: f32 -> bf16 convert (W_in) ----------------
__global__ __launch_bounds__(256) void k_cvt(const float* __restrict__ in,
                                             unsigned short* __restrict__ out, int n4) {
  int i = blockIdx.x * 256 + threadIdx.x;
  if (i < n4) {
    float4 v = ((const float4*)in)[i];
    ushort4 o;
    o.x = f2bf(v.x); o.y = f2bf(v.y); o.z = f2bf(v.z); o.w = f2bf(v.w);
    ((ushort4*)out)[i] = o;
  }
}

// ---------------- Kernel P: split hidden -> bf16 hi plane + lo plane ----------------
__global__ __launch_bounds__(256) void k_pack(const float* __restrict__ hid,
                                              unsigned short* __restrict__ Phi,
                                              unsigned short* __restrict__ Plo) {
  int i = blockIdx.x * 256 + threadIdx.x;   // f32x4 index, total NB*SLEN*HID/4
  float4 x = ((const float4*)hid)[i];
  float e[4] = {x.x, x.y, x.z, x.w};
  ushort4 hv, lv;
  unsigned short* hp = (unsigned short*)&hv;
  unsigned short* lp = (unsigned short*)&lv;
#pragma unroll
  for (int j = 0; j < 4; ++j) {
    u32 u = __float_as_uint(e[j]);
    u32 hb = (u + 0x7fffu + ((u >> 16) & 1u)) >> 16;
    float r = e[j] - __uint_as_float(hb << 16);
    u32 ur = __float_as_uint(r);
    u32 lb = (ur + 0x7fffu + ((ur >> 16) & 1u)) >> 16;
    hp[j] = (unsigned short)hb;
    lp[j] = (unsigned short)lb;
  }
  ((ushort4*)Phi)[i] = hv;
  ((ushort4*)Plo)[i] = lv;
}

// ---------------- Kernel B: persistent-block MFMA scores ----------------
// 256 blocks (1/CU). Block (xcd=bid&7, j=bid>>3) processes units u=j,j+32,...
// of its XCD's 112 (bh,qt) units -> 2-3 K-panels live per XCD L2 at a time.
// Per unit: 32 q rows x 1024 k, triple-buffered K staging, counted vmcnt(4),
// raw barriers (no drains). exp(scores) kept in registers e[32][4].
__global__ __launch_bounds__(256) void k_scores(const unsigned short* __restrict__ Phi,
                                                const unsigned short* __restrict__ Plo,
                                                float* __restrict__ part) {
  __shared__ unsigned short Kh[3][KT * HD];   // 3 x 8 KB
  __shared__ unsigned short Kl[3][KT * HD];   // 3 x 8 KB
  __shared__ float cs[2][SLEN];               // 8 KB
  __shared__ float zbuf[2][QT];               // 256 B

  int bid = blockIdx.x;
  int xcd = bid & 7, j0 = bid >> 3;           // j0 in 0..31
  int t = threadIdx.x, l = t & 63, wv = t >> 6;
  int wq = wv & 1, wk = wv >> 1;

  // staging geometry (unit-independent): thread covers granules sg0, sg1
  int sg0 = (wv * 2 + 0) * 64 + l;
  int sg1 = (wv * 2 + 1) * 64 + l;
  int srow0 = sg0 >> 4, srow1 = sg1 >> 4;
  size_t soff0 = (size_t)srow0 * HID + ((sg0 & 15) ^ (srow0 & 7)) * 8;
  size_t soff1 = (size_t)srow1 * HID + ((sg1 & 15) ^ (srow1 & 7)) * 8;

  // fragment read offsets (XOR-swizzled)
  int frow = wk * 16 + (l & 15);
  int foff[4];
#pragma unroll
  for (int ds = 0; ds < 4; ++ds)
    foff[ds] = frow * HD + (((ds * 4) + (l >> 4)) ^ (frow & 7)) * 8;

  const float scale = 0.088388347648318447f;  // 1/sqrt(128)

  for (int u = j0; u < 112; u += 32) {
    int bh = xcd * 8 + u / NQT;
    int qt = u % NQT;
    int b = bh >> 5, h = bh & 31;
    const unsigned short* PhB = Phi + (size_t)b * SLEN * HID + h * HD;
    const unsigned short* PlB = Plo + (size_t)b * SLEN * HID + h * HD;

#define STAGE(kt_, bb_)                                                        \
  do {                                                                         \
    size_t kb_ = (size_t)(kt_)*KT * HID;                                       \
    load_lds16(PhB + kb_ + soff0, &Kh[bb_][sg0 * 8]);                          \
    load_lds16(PlB + kb_ + soff0, &Kl[bb_][sg0 * 8]);                          \
    load_lds16(PhB + kb_ + soff1, &Kh[bb_][sg1 * 8]);                          \
    load_lds16(PlB + kb_ + soff1, &Kl[bb_][sg1 * 8]);                          \
  } while (0)

    // Q fragments for this unit
    bf16x8 qhi[4], qlo[4];
    {
      int ql = qt * QT + wq * 16 + (l & 15);
      int qg = (ql < OFF) ? ql : ql + VT;
      const unsigned short* ph = PhB + (size_t)qg * HID + (l >> 4) * 8;
      const unsigned short* pl = PlB + (size_t)qg * HID + (l >> 4) * 8;
#pragma unroll
      for (int ds = 0; ds < 4; ++ds) {
        qhi[ds] = *(const bf16x8*)(ph + ds * 32);
        qlo[ds] = *(const bf16x8*)(pl + ds * 32);
      }
    }

    STAGE(0, 0);
    STAGE(1, 1);

    float e[NKT][4];

#pragma unroll
    for (int tt = 0; tt < NKT; ++tt) {
      int bb = tt % 3;
      // gate tile tt (own loads: only tile tt+1's 4 may remain), then barrier
      if (tt < NKT - 1) {
        asm volatile("s_waitcnt vmcnt(4)" ::: "memory");
      } else {
        asm volatile("s_waitcnt vmcnt(0)" ::: "memory");
      }
      __builtin_amdgcn_s_barrier();
      __builtin_amdgcn_sched_barrier(0);

      bf16x8 kh[4], kl[4];
#pragma unroll
      for (int ds = 0; ds < 4; ++ds) {
        kh[ds] = *(const bf16x8*)&Kh[bb][foff[ds]];
        kl[ds] = *(const bf16x8*)&Kl[bb][foff[ds]];
      }
      if (tt + 2 < NKT) STAGE(tt + 2, (tt + 2) % 3);

      f32x4 aP = {0.f, 0.f, 0.f, 0.f};
      f32x4 aQ = {0.f, 0.f, 0.f, 0.f};
      f32x4 aR = {0.f, 0.f, 0.f, 0.f};
#pragma unroll
      for (int ds = 0; ds < 4; ++ds) {
        aP = __builtin_amdgcn_mfma_f32_16x16x32_bf16(qhi[ds], kh[ds], aP, 0, 0, 0);
        aQ = __builtin_amdgcn_mfma_f32_16x16x32_bf16(qhi[ds], kl[ds], aQ, 0, 0, 0);
        aR = __builtin_amdgcn_mfma_f32_16x16x32_bf16(qlo[ds], kh[ds], aR, 0, 0, 0);
      }
#pragma unroll
      for (int jj = 0; jj < 4; ++jj)
        e[tt][jj] = __expf((aP[jj] + aQ[jj] + aR[jj]) * scale);
    }
#undef STAGE

    // ---- z per row ----
    float zr[4] = {0.f, 0.f, 0.f, 0.f};
#pragma unroll
    for (int tt = 0; tt < NKT; ++tt)
#pragma unroll
      for (int jj = 0; jj < 4; ++jj) zr[jj] += e[tt][jj];
#pragma unroll
    for (int jj = 0; jj < 4; ++jj) {
      float z = zr[jj];
      z += __shfl_xor(z, 1);
      z += __shfl_xor(z, 2);
      z += __shfl_xor(z, 4);
      z += __shfl_xor(z, 8);
      zr[jj] = z;
    }
    if ((l & 15) == 0) {
#pragma unroll
      for (int jj = 0; jj < 4; ++jj)
        zbuf[wk][wq * 16 + (l >> 4) * 4 + jj] = zr[jj];
    }
    __syncthreads();

    float zinv[4];
#pragma unroll
    for (int jj = 0; jj < 4; ++jj) {
      int row = wq * 16 + (l >> 4) * 4 + jj;
      zinv[jj] = 1.f / (zbuf[0][row] + zbuf[1][row]);
    }

#pragma unroll
    for (int tt = 0; tt < NKT; ++tt) {
      float v = e[tt][0] * zinv[0] + e[tt][1] * zinv[1] +
                e[tt][2] * zinv[2] + e[tt][3] * zinv[3];
      v += __shfl_xor(v, 16);
      v += __shfl_xor(v, 32);
      if (l < 16) cs[wq][tt * KT + wk * 16 + l] = v;
    }
    __syncthreads();

    for (int c5 = t; c5 < VT; c5 += 256) {
      int col = OFF + c5;
      part[((size_t)bh * NQT + qt) * VT + c5] = cs[0][col] + cs[1][col];
    }
    __syncthreads();   // LDS safe for next unit
  }
}

// ---------------- Kernel C: per-head softmax / pool / argmax / w ----------------
__global__ __launch_bounds__(256) void k_head(const float* __restrict__ part,
                                              float* __restrict__ params) {
  int bh = blockIdx.x;
  int t = threadIdx.x;
  __shared__ float ia[VT];
  __shared__ float sfe[VT];
  __shared__ float rbuf[256];
  __shared__ int ribuf[256];

  for (int i = t; i < VT; i += 256) {
    float s = 0.f;
    const float* p = part + (size_t)bh * NQT * VT + i;
    for (int c = 0; c < NQT; ++c) s += p[(size_t)c * VT];
    ia[i] = s;
  }
  __syncthreads();

  float lm = -1e30f;
  for (int i = t; i < VT; i += 256) lm = fmaxf(lm, ia[i]);
  rbuf[t] = lm;
  __syncthreads();
  for (int s = 128; s > 0; s >>= 1) {
    if (t < s) rbuf[t] = fmaxf(rbuf[t], rbuf[t + s]);
    __syncthreads();
  }
  float M = rbuf[0];
  __syncthreads();

  float lz = 0.f;
  for (int i = t; i < VT; i += 256) {
    float e = __expf(ia[i] - M);
    sfe[i] = e;
    lz += e;
  }
  rbuf[t] = lz;
  __syncthreads();
  for (int s = 128; s > 0; s >>= 1) {
    if (t < s) rbuf[t] += rbuf[t + s];
    __syncthreads();
  }
  float invZ = 1.f / rbuf[0];
  __syncthreads();

  float pv = -1e30f;
  int pidx = 0x7fffffff;
  if (t < PEW * PEW) {
    int r = t / PEW, c = t % PEW;
    float s = 0.f;
    for (int i = 0; i < KW; ++i)
      for (int j = 0; j < KW; ++j) s += ia[(r + i) * EDGE + (c + j)];
    pv = s;
    pidx = t;
  }
  rbuf[t] = pv;
  ribuf[t] = pidx;
  __syncthreads();
  for (int s = 128; s > 0; s >>= 1) {
    if (t < s) {
      float ov = rbuf[t + s];
      int oi = ribuf[t + s];
      if (ov > rbuf[t] || (ov == rbuf[t] && oi < ribuf[t])) {
        rbuf[t] = ov;
        ribuf[t] = oi;
      }
    }
    __syncthreads();
  }
  int idx = ribuf[0];
  int r0 = idx / PEW, c0 = idx % PEW;
  __syncthreads();

  float lw = 0.f;
  if (t < KW * KW) {
    int i = t / KW, j = t % KW;
    lw = sfe[(r0 + i) * EDGE + (c0 + j)];
  }
  rbuf[t] = lw;
  __syncthreads();
  for (int s = 128; s > 0; s >>= 1) {
    if (t < s) rbuf[t] += rbuf[t + s];
    __syncthreads();
  }
  if (t == 0) {
    params[bh * 4 + 0] = rbuf[0] * invZ;
    ((int*)params)[bh * 4 + 1] = r0;
    ((int*)params)[bh * 4 + 2] = c0;
  }
}

// ---------------- Kernel D2: per-head window up-projection -> bf16 into Phi ----------------
__global__ __launch_bounds__(256) void k_img(const float* __restrict__ hid,
                                             const float* __restrict__ Wup,
                                             const float* __restrict__ params,
                                             unsigned short* __restrict__ hs) {
  int bid = blockIdx.x;
  int g = bid & 3;
  int bh = bid >> 2;
  int b = bh / NH, h = bh % NH;
  float w = params[bh * 4];
  int r0 = ((const int*)params)[bh * 4 + 1];
  int c0 = ((const int*)params)[bh * 4 + 2];
  int t = threadIdx.x;

  __shared__ float win[36][HD];
  for (int idx = t; idx < 36 * (HD / 4); idx += 256) {
    int cell = idx >> 5;
    int c4 = idx & 31;
    int cc = g * 36 + cell;
    int i = cc / 12, j = cc % 12;
    int s = OFF + (r0 + i) * EDGE + (c0 + j);
    *(float4*)&win[cell][c4 * 4] =
        *(const float4*)(hid + ((size_t)(b * SLEN + s)) * HID + h * HD + c4 * 4);
  }
  __syncthreads();

  float acc0[36], acc1[36];
#pragma unroll
  for (int cell = 0; cell < 36; ++cell) { acc0[cell] = 0.f; acc1[cell] = 0.f; }

  int e0 = t, e1 = t + 256;
  const float* w0 = Wup + (size_t)e0 * HD;
  const float* w1 = Wup + (size_t)e1 * HD;
  for (int c = 0; c < 32; ++c) {
    float4 u0 = *(const float4*)(w0 + c * 4);
    float4 u1 = *(const float4*)(w1 + c * 4);
#pragma unroll
    for (int cell = 0; cell < 36; ++cell) {
      float4 qv = *(const float4*)&win[cell][c * 4];
      acc0[cell] += dot4(qv, u0);
      acc1[cell] += dot4(qv, u1);
    }
  }

  int si0 = e0 >> 8, sj0 = (e0 >> 7) & 1, d0 = e0 & 127;
  int si1 = e1 >> 8, sj1 = (e1 >> 7) & 1, d1 = e1 & 127;
#pragma unroll
  for (int cell = 0; cell < 36; ++cell) {
    int cc = g * 36 + cell;
    int i = cc / 12, j = cc % 12;
    {
      int srow = OFF + (2 * i + si0) * EDGE + (2 * j + sj0);
      hs[((size_t)(b * SLEN + srow)) * HID + h * HD + d0] = f2bf(acc0[cell] * w);
    }
    {
      int srow = OFF + (2 * i + si1) * EDGE + (2 * j + sj1);
      hs[((size_t)(b * SLEN + srow)) * HID + h * HD + d1] = f2bf(acc1[cell] * w);
    }
  }
}

// ---------------- Kernel E: single-barrier counted-vmcnt bf16 MFMA GEMM ----------------
// C[m,e] = resid[m,e] + silu( sum_d A[m,d] * W[e,d] ),  M=2048, N=K=4096.
// BM=128, BN=256, BK=64; 256 blocks (1/CU), 512 threads (8 waves, 2Mx4N).
// Triple-buffered LDS, depth-2 prefetch, ONE vmcnt(6)+barrier per K-tile;
// compiler free to interleave ds_reads / stage-issues / MFMAs within the tile.
__global__ __launch_bounds__(512, 2) void k_gemm(const unsigned short* __restrict__ A,
                                                 const unsigned short* __restrict__ Bm,
                                                 const float* __restrict__ resid,
                                                 float* __restrict__ out) {
  __shared__ unsigned short lA[3][128 * 64];   // 48 KB
  __shared__ unsigned short lB[3][256 * 64];   // 96 KB

  int bid0 = blockIdx.x;
  int swz = (bid0 & 7) * 32 + (bid0 >> 3);     // XCD-contiguous (256 % 8 == 0)
  int bm0 = (swz & 15) << 7;
  int bn0 = (swz >> 4) << 8;                   // each XCD: 512-col B slice = 4 MB L2
  int t = threadIdx.x;
  int ln = t & 63, wv = t >> 6;
  int wr = wv >> 2, wc = wv & 3;               // 2 x 4 wave grid, 64x64 C per wave

  // fragment read offsets (XOR-swizzled 16B granules)
  int aOff[4][2], bOff[4][2];
#pragma unroll
  for (int q = 0; q < 4; ++q)
#pragma unroll
    for (int ks = 0; ks < 2; ++ks) {
      int ga = ks * 4 + (ln >> 4);
      int ra = wr * 64 + q * 16 + (ln & 15);
      aOff[q][ks] = ra * 64 + ((ga ^ (ra & 7)) * 8);
      int rb = wc * 64 + q * 16 + (ln & 15);
      bOff[q][ks] = rb * 64 + ((ga ^ (rb & 7)) * 8);
    }

  // staging: linear LDS dest granules, inverse-swizzled global source cols
  const unsigned short* aS0; const unsigned short* aS1;
  unsigned short *aD0, *aD1;
  {
    int G = t, r = G >> 3, g = G & 7;
    aS0 = A + (size_t)(bm0 + r) * HID + ((g ^ (r & 7)) * 8);
    aD0 = &lA[0][0] + G * 8;
    G = t + 512; r = G >> 3; g = G & 7;
    aS1 = A + (size_t)(bm0 + r) * HID + ((g ^ (r & 7)) * 8);
    aD1 = &lA[0][0] + G * 8;
  }
  const unsigned short *bS0, *bS1, *bS2, *bS3;
  unsigned short *bD0, *bD1, *bD2, *bD3;
  {
    int G = t, r = G >> 3, g = G & 7;
    bS0 = Bm + (size_t)(bn0 + r) * HID + ((g ^ (r & 7)) * 8);
    bD0 = &lB[0][0] + G * 8;
    G = t + 512; r = G >> 3; g = G & 7;
    bS1 = Bm + (size_t)(bn0 + r) * HID + ((g ^ (r & 7)) * 8);
    bD1 = &lB[0][0] + G * 8;
    G = t + 1024; r = G >> 3; g = G & 7;
    bS2 = Bm + (size_t)(bn0 + r) * HID + ((g ^ (r & 7)) * 8);
    bD2 = &lB[0][0] + G * 8;
    G = t + 1536; r = G >> 3; g = G & 7;
    bS3 = Bm + (size_t)(bn0 + r) * HID + ((g ^ (r & 7)) * 8);
    bD3 = &lB[0][0] + G * 8;
  }

#define STAGE_ALL(kt_, nb_)                                \
  load_lds16(aS0 + (kt_) * 64, aD0 + (nb_) * 8192);        \
  load_lds16(aS1 + (kt_) * 64, aD1 + (nb_) * 8192);        \
  load_lds16(bS0 + (kt_) * 64, bD0 + (nb_) * 16384);       \
  load_lds16(bS1 + (kt_) * 64, bD1 + (nb_) * 16384);       \
  load_lds16(bS2 + (kt_) * 64, bD2 + (nb_) * 16384);       \
  load_lds16(bS3 + (kt_) * 64, bD3 + (nb_) * 16384);

  f32x4 acc[4][4];
#pragma unroll
  for (int mi = 0; mi < 4; ++mi)
#pragma unroll
    for (int ni = 0; ni < 4; ++ni) acc[mi][ni] = (f32x4){0.f, 0.f, 0.f, 0.f};

  // prologue: stage tiles 0 and 1 (6 loads each)
  STAGE_ALL(0, 0);
  STAGE_ALL(1, 1);

  int cur = 0;
  for (int kt = 0; kt < 64; ++kt) {
    // gate: tile kt resident for ALL waves, then one barrier
    if (kt < 63) {
      asm volatile("s_waitcnt vmcnt(6)" ::: "memory");
    } else {
      asm volatile("s_waitcnt vmcnt(0)" ::: "memory");
    }
    __builtin_amdgcn_s_barrier();
    __builtin_amdgcn_sched_barrier(0);

    const unsigned short* Ab = &lA[0][0] + cur * 8192;
    const unsigned short* Bb = &lB[0][0] + cur * 16384;

    bf16x8 aF[4][2], bF[4][2];
#pragma unroll
    for (int q = 0; q < 4; ++q) {
      aF[q][0] = *(const bf16x8*)(Ab + aOff[q][0]);
      aF[q][1] = *(const bf16x8*)(Ab + aOff[q][1]);
      bF[q][0] = *(const bf16x8*)(Bb + bOff[q][0]);
      bF[q][1] = *(const bf16x8*)(Bb + bOff[q][1]);
    }

    int nb = cur + 2; if (nb >= 3) nb -= 3;
    if (kt < 62) { STAGE_ALL(kt + 2, nb); }

    __builtin_amdgcn_s_setprio(1);
#pragma unroll
    for (int ni = 0; ni < 4; ++ni)
#pragma unroll
      for (int mi = 0; mi < 4; ++mi) {
        acc[mi][ni] = __builtin_amdgcn_mfma_f32_16x16x32_bf16(aF[mi][0], bF[ni][0],
                                                              acc[mi][ni], 0, 0, 0);
        acc[mi][ni] = __builtin_amdgcn_mfma_f32_16x16x32_bf16(aF[mi][1], bF[ni][1],
                                                              acc[mi][ni], 0, 0, 0);
      }
    __builtin_amdgcn_s_setprio(0);

    cur = cur + 1; if (cur >= 3) cur = 0;
  }
#undef STAGE_ALL

  // epilogue: silu + residual, f32 out
#pragma unroll
  for (int mi = 0; mi < 4; ++mi) {
#pragma unroll
    for (int ni = 0; ni < 4; ++ni) {
      int m = bm0 + wr * 64 + mi * 16 + (ln >> 4) * 4;
      int n = bn0 + wc * 64 + ni * 16 + (ln & 15);
#pragma unroll
      for (int r = 0; r < 4; ++r) {
        float x = acc[mi][ni][r];
        float s = x / (1.f + __expf(-x));
        size_t o = (size_t)(m + r) * HID + n;
        out[o] = resid[o] + s;
      }
    }
  }
}

extern "C" void kernel_launch(void* const* d_in, const int* in_sizes, int n_in,
                              void* d_out, int out_size, void* d_ws, size_t ws_size,
                              hipStream_t stream) {
  const float* hid = (const float*)d_in[0];
  const float* Win = (const float*)d_in[1];
  const float* Wup = (const float*)d_in[2];
  float* out = (float*)d_out;
  char* ws = (char*)d_ws;

  unsigned short* Wb  = (unsigned short*)ws;                 // 33,554,432 B
  unsigned short* Phi = (unsigned short*)(ws + 33554432);    // 16,777,216 B
  float* part = (float*)(ws + 50331648);                     //  2,064,384 B
  float* params = (float*)(ws + 52396032);                   //      1,024 B
  unsigned short* Plo = (unsigned short*)d_out;  // lo plane lives in d_out until k_gemm

  k_cvt<<<16384, 256, 0, stream>>>(Win, Wb, HID * HID / 4);
  k_pack<<<NB * SLEN * HID / 4 / 256, 256, 0, stream>>>(hid, Phi, Plo);
  k_scores<<<256, 256, 0, stream>>>(Phi, Plo, part);
  k_head<<<NB * NH, 256, 0, stream>>>(part, params);
  k_img<<<NB * NH * 4, 256, 0, stream>>>(hid, Wup, params, Phi);
  k_gemm<<<256, 512, 0, stream>>>(Phi, Wb, hid, out);
}

// Round 7
// 193.641 us; speedup vs baseline: 2.2786x; 1.1275x over previous
//
#include <hip/hip_runtime.h>
#include <hip/hip_bf16.h>
#include <math.h>

#define HID 4096
#define NH 32
#define HD 128
#define EDGE 24
#define KW 12
#define PEW 13
#define VT 576
#define OFF 5
#define NB 2
#define SLEN 1024
#define QT 64      // q rows per scores block
#define NQT 7      // q tiles per (b,h)  (448/64)
#define KT 64      // k rows per staged tile
#define NKT 16     // 1024/KT

typedef short bf16x8 __attribute__((ext_vector_type(8)));
typedef float f32x4 __attribute__((ext_vector_type(4)));
typedef unsigned int u32;

static __device__ __forceinline__ unsigned short f2bf(float f) {
  union { float f; u32 u; } v; v.f = f;
  u32 u = v.u;
  return (unsigned short)((u + 0x7fffu + ((u >> 16) & 1u)) >> 16);
}

static __device__ __forceinline__ float dot4(float4 a, float4 b) {
  return a.x * b.x + a.y * b.y + a.z * b.z + a.w * b.w;
}

static __device__ __forceinline__ void load_lds16(const void* g, void* l) {
  __builtin_amdgcn_global_load_lds((const __attribute__((address_space(1))) u32*)g,
                                   (__attribute__((address_space(3))) u32*)l, 16, 0, 0);
}

// ---------------- Kernel A: f32 -> bf16 convert (W_in) ----------------
__global__ __launch_bounds__(256) void k_cvt(const float* __restrict__ in,
                                             unsigned short* __restrict__ out, int n4) {
  int i = blockIdx.x * 256 + threadIdx.x;
  if (i < n4) {
    float4 v = ((const float4*)in)[i];
    ushort4 o;
    o.x = f2bf(v.x); o.y = f2bf(v.y); o.z = f2bf(v.z); o.w = f2bf(v.w);
    ((ushort4*)out)[i] = o;
  }
}

// ---------------- Kernel P: split hidden -> bf16 hi plane + lo plane ----------------
__global__ __launch_bounds__(256) void k_pack(const float* __restrict__ hid,
                                              unsigned short* __restrict__ Phi,
                                              unsigned short* __restrict__ Plo) {
  int i = blockIdx.x * 256 + threadIdx.x;   // f32x4 index, total NB*SLEN*HID/4
  float4 x = ((const float4*)hid)[i];
  float e[4] = {x.x, x.y, x.z, x.w};
  ushort4 hv, lv;
  unsigned short* hp = (unsigned short*)&hv;
  unsigned short* lp = (unsigned short*)&lv;
#pragma unroll
  for (int j = 0; j < 4; ++j) {
    u32 u = __float_as_uint(e[j]);
    u32 hb = (u + 0x7fffu + ((u >> 16) & 1u)) >> 16;
    float r = e[j] - __uint_as_float(hb << 16);
    u32 ur = __float_as_uint(r);
    u32 lb = (ur + 0x7fffu + ((ur >> 16) & 1u)) >> 16;
    hp[j] = (unsigned short)hb;
    lp[j] = (unsigned short)lb;
  }
  ((ushort4*)Phi)[i] = hv;
  ((ushort4*)Plo)[i] = lv;
}

// ---------------- Kernel B: 8-wave MFMA scores (QT=64, KT=64) ----------------
// grid = 448 (xcd = bid&7 -> own 8 heads). Block: one (b,h), 64 q rows.
// 8 waves: wq=wv>>1 (16-row group), wk=wv&1 (32-col half of each 64-col tile).
// Triple-buffered K staging (96 KB), counted vmcnt(4), one barrier per tile.
// exp(scores) kept in registers e[16][2][4] (static indices only).
__global__ __launch_bounds__(512, 2) void k_scores(const unsigned short* __restrict__ Phi,
                                                   const unsigned short* __restrict__ Plo,
                                                   float* __restrict__ part) {
  __shared__ unsigned short Kh[3][KT * HD];   // 3 x 16 KB
  __shared__ unsigned short Kl[3][KT * HD];   // 3 x 16 KB
  __shared__ float cs[4][SLEN];               // 16 KB
  __shared__ float zbuf[2][QT];               // 512 B

  int bid = blockIdx.x;
  int xcd = bid & 7, idx = bid >> 3;          // idx in 0..55
  int bh = xcd * 8 + idx / NQT;
  int qt = idx % NQT;
  int b = bh >> 5, h = bh & 31;
  int t = threadIdx.x, l = t & 63, wv = t >> 6;
  int wq = wv >> 1, wk = wv & 1;

  const unsigned short* PhB = Phi + (size_t)b * SLEN * HID + h * HD;
  const unsigned short* PlB = Plo + (size_t)b * SLEN * HID + h * HD;

  // ---- Q fragments: wave's 16 q rows, 4 K-dim slices ----
  bf16x8 qhi[4], qlo[4];
  {
    int ql = qt * QT + wq * 16 + (l & 15);
    int qg = (ql < OFF) ? ql : ql + VT;
    const unsigned short* ph = PhB + (size_t)qg * HID + (l >> 4) * 8;
    const unsigned short* pl = PlB + (size_t)qg * HID + (l >> 4) * 8;
#pragma unroll
    for (int ds = 0; ds < 4; ++ds) {
      qhi[ds] = *(const bf16x8*)(ph + ds * 32);
      qlo[ds] = *(const bf16x8*)(pl + ds * 32);
    }
  }

  // staging: 1024 granules/plane/tile; thread covers g0=t, g1=t+512.
  // linear LDS dest, inverse-swizzled global source column.
  int g0 = t, g1 = t + 512;
  int r0 = g0 >> 4, r1 = g1 >> 4;
  size_t soff0 = (size_t)r0 * HID + ((g0 & 15) ^ (r0 & 7)) * 8;
  size_t soff1 = (size_t)r1 * HID + ((g1 & 15) ^ (r1 & 7)) * 8;

#define STAGE(kt_, bb_)                                                        \
  do {                                                                         \
    size_t kb_ = (size_t)(kt_)*KT * HID;                                       \
    load_lds16(PhB + kb_ + soff0, &Kh[bb_][g0 * 8]);                           \
    load_lds16(PhB + kb_ + soff1, &Kh[bb_][g1 * 8]);                           \
    load_lds16(PlB + kb_ + soff0, &Kl[bb_][g0 * 8]);                           \
    load_lds16(PlB + kb_ + soff1, &Kl[bb_][g1 * 8]);                           \
  } while (0)

  const float scale = 0.088388347648318447f;  // 1/sqrt(128)

  // fragment read offsets (XOR-swizzled granules): col-frag c, K-slice ds
  int foff[2][4];
#pragma unroll
  for (int c = 0; c < 2; ++c) {
    int rb = wk * 32 + c * 16 + (l & 15);
#pragma unroll
    for (int ds = 0; ds < 4; ++ds)
      foff[c][ds] = rb * HD + (((ds * 4) + (l >> 4)) ^ (rb & 7)) * 8;
  }

  float e[NKT][2][4];

  STAGE(0, 0);
  STAGE(1, 1);

#pragma unroll
  for (int tt = 0; tt < NKT; ++tt) {
    int bb = tt % 3;
    if (tt < NKT - 1) {
      asm volatile("s_waitcnt vmcnt(4)" ::: "memory");
    } else {
      asm volatile("s_waitcnt vmcnt(0)" ::: "memory");
    }
    __builtin_amdgcn_s_barrier();
    __builtin_amdgcn_sched_barrier(0);

    bf16x8 kh[2][4], kl[2][4];
#pragma unroll
    for (int c = 0; c < 2; ++c)
#pragma unroll
      for (int ds = 0; ds < 4; ++ds) {
        kh[c][ds] = *(const bf16x8*)&Kh[bb][foff[c][ds]];
        kl[c][ds] = *(const bf16x8*)&Kl[bb][foff[c][ds]];
      }
    if (tt + 2 < NKT) STAGE(tt + 2, (tt + 2) % 3);

#pragma unroll
    for (int c = 0; c < 2; ++c) {
      f32x4 aP = {0.f, 0.f, 0.f, 0.f};
      f32x4 aQ = {0.f, 0.f, 0.f, 0.f};
      f32x4 aR = {0.f, 0.f, 0.f, 0.f};
#pragma unroll
      for (int ds = 0; ds < 4; ++ds) {
        aP = __builtin_amdgcn_mfma_f32_16x16x32_bf16(qhi[ds], kh[c][ds], aP, 0, 0, 0);
        aQ = __builtin_amdgcn_mfma_f32_16x16x32_bf16(qhi[ds], kl[c][ds], aQ, 0, 0, 0);
        aR = __builtin_amdgcn_mfma_f32_16x16x32_bf16(qlo[ds], kh[c][ds], aR, 0, 0, 0);
      }
#pragma unroll
      for (int jj = 0; jj < 4; ++jj)
        e[tt][c][jj] = __expf((aP[jj] + aQ[jj] + aR[jj]) * scale);
    }
  }
#undef STAGE

  // ---- z per row: sum over tiles+col-frags, shfl across the 16 col-lanes ----
  float zr[4] = {0.f, 0.f, 0.f, 0.f};
#pragma unroll
  for (int tt = 0; tt < NKT; ++tt)
#pragma unroll
    for (int c = 0; c < 2; ++c)
#pragma unroll
      for (int jj = 0; jj < 4; ++jj) zr[jj] += e[tt][c][jj];
#pragma unroll
  for (int jj = 0; jj < 4; ++jj) {
    float z = zr[jj];
    z += __shfl_xor(z, 1);
    z += __shfl_xor(z, 2);
    z += __shfl_xor(z, 4);
    z += __shfl_xor(z, 8);
    zr[jj] = z;
  }
  if ((l & 15) == 0) {
#pragma unroll
    for (int jj = 0; jj < 4; ++jj)
      zbuf[wk][wq * 16 + (l >> 4) * 4 + jj] = zr[jj];
  }
  __syncthreads();

  float zinv[4];
#pragma unroll
  for (int jj = 0; jj < 4; ++jj) {
    int row = wq * 16 + (l >> 4) * 4 + jj;
    zinv[jj] = 1.f / (zbuf[0][row] + zbuf[1][row]);
  }

  // ---- colsums: per tile/col-frag, reduce over the wave's 16 q rows ----
#pragma unroll
  for (int tt = 0; tt < NKT; ++tt)
#pragma unroll
    for (int c = 0; c < 2; ++c) {
      float v = e[tt][c][0] * zinv[0] + e[tt][c][1] * zinv[1] +
                e[tt][c][2] * zinv[2] + e[tt][c][3] * zinv[3];
      v += __shfl_xor(v, 16);
      v += __shfl_xor(v, 32);
      if (l < 16) cs[wq][tt * KT + wk * 32 + c * 16 + l] = v;
    }
  __syncthreads();

  for (int c5 = t; c5 < VT; c5 += 512) {
    int col = OFF + c5;
    part[((size_t)bh * NQT + qt) * VT + c5] =
        (cs[0][col] + cs[1][col]) + (cs[2][col] + cs[3][col]);
  }
}

// ---------------- Kernel C: per-head softmax / pool / argmax / w ----------------
__global__ __launch_bounds__(256) void k_head(const float* __restrict__ part,
                                              float* __restrict__ params) {
  int bh = blockIdx.x;
  int t = threadIdx.x;
  __shared__ float ia[VT];
  __shared__ float sfe[VT];
  __shared__ float rbuf[256];
  __shared__ int ribuf[256];

  for (int i = t; i < VT; i += 256) {
    float s = 0.f;
    const float* p = part + (size_t)bh * NQT * VT + i;
    for (int c = 0; c < NQT; ++c) s += p[(size_t)c * VT];
    ia[i] = s;
  }
  __syncthreads();

  float lm = -1e30f;
  for (int i = t; i < VT; i += 256) lm = fmaxf(lm, ia[i]);
  rbuf[t] = lm;
  __syncthreads();
  for (int s = 128; s > 0; s >>= 1) {
    if (t < s) rbuf[t] = fmaxf(rbuf[t], rbuf[t + s]);
    __syncthreads();
  }
  float M = rbuf[0];
  __syncthreads();

  float lz = 0.f;
  for (int i = t; i < VT; i += 256) {
    float e = __expf(ia[i] - M);
    sfe[i] = e;
    lz += e;
  }
  rbuf[t] = lz;
  __syncthreads();
  for (int s = 128; s > 0; s >>= 1) {
    if (t < s) rbuf[t] += rbuf[t + s];
    __syncthreads();
  }
  float invZ = 1.f / rbuf[0];
  __syncthreads();

  float pv = -1e30f;
  int pidx = 0x7fffffff;
  if (t < PEW * PEW) {
    int r = t / PEW, c = t % PEW;
    float s = 0.f;
    for (int i = 0; i < KW; ++i)
      for (int j = 0; j < KW; ++j) s += ia[(r + i) * EDGE + (c + j)];
    pv = s;
    pidx = t;
  }
  rbuf[t] = pv;
  ribuf[t] = pidx;
  __syncthreads();
  for (int s = 128; s > 0; s >>= 1) {
    if (t < s) {
      float ov = rbuf[t + s];
      int oi = ribuf[t + s];
      if (ov > rbuf[t] || (ov == rbuf[t] && oi < ribuf[t])) {
        rbuf[t] = ov;
        ribuf[t] = oi;
      }
    }
    __syncthreads();
  }
  int idx = ribuf[0];
  int r0 = idx / PEW, c0 = idx % PEW;
  __syncthreads();

  float lw = 0.f;
  if (t < KW * KW) {
    int i = t / KW, j = t % KW;
    lw = sfe[(r0 + i) * EDGE + (c0 + j)];
  }
  rbuf[t] = lw;
  __syncthreads();
  for (int s = 128; s > 0; s >>= 1) {
    if (t < s) rbuf[t] += rbuf[t + s];
    __syncthreads();
  }
  if (t == 0) {
    params[bh * 4 + 0] = rbuf[0] * invZ;
    ((int*)params)[bh * 4 + 1] = r0;
    ((int*)params)[bh * 4 + 2] = c0;
  }
}

// ---------------- Kernel D2: per-head window up-projection -> bf16 into Phi ----------------
__global__ __launch_bounds__(256) void k_img(const float* __restrict__ hid,
                                             const float* __restrict__ Wup,
                                             const float* __restrict__ params,
                                             unsigned short* __restrict__ hs) {
  int bid = blockIdx.x;
  int g = bid & 3;
  int bh = bid >> 2;
  int b = bh / NH, h = bh % NH;
  float w = params[bh * 4];
  int r0 = ((const int*)params)[bh * 4 + 1];
  int c0 = ((const int*)params)[bh * 4 + 2];
  int t = threadIdx.x;

  __shared__ float win[36][HD];
  for (int idx = t; idx < 36 * (HD / 4); idx += 256) {
    int cell = idx >> 5;
    int c4 = idx & 31;
    int cc = g * 36 + cell;
    int i = cc / 12, j = cc % 12;
    int s = OFF + (r0 + i) * EDGE + (c0 + j);
    *(float4*)&win[cell][c4 * 4] =
        *(const float4*)(hid + ((size_t)(b * SLEN + s)) * HID + h * HD + c4 * 4);
  }
  __syncthreads();

  float acc0[36], acc1[36];
#pragma unroll
  for (int cell = 0; cell < 36; ++cell) { acc0[cell] = 0.f; acc1[cell] = 0.f; }

  int e0 = t, e1 = t + 256;
  const float* w0 = Wup + (size_t)e0 * HD;
  const float* w1 = Wup + (size_t)e1 * HD;
  for (int c = 0; c < 32; ++c) {
    float4 u0 = *(const float4*)(w0 + c * 4);
    float4 u1 = *(const float4*)(w1 + c * 4);
#pragma unroll
    for (int cell = 0; cell < 36; ++cell) {
      float4 qv = *(const float4*)&win[cell][c * 4];
      acc0[cell] += dot4(qv, u0);
      acc1[cell] += dot4(qv, u1);
    }
  }

  int si0 = e0 >> 8, sj0 = (e0 >> 7) & 1, d0 = e0 & 127;
  int si1 = e1 >> 8, sj1 = (e1 >> 7) & 1, d1 = e1 & 127;
#pragma unroll
  for (int cell = 0; cell < 36; ++cell) {
    int cc = g * 36 + cell;
    int i = cc / 12, j = cc % 12;
    {
      int srow = OFF + (2 * i + si0) * EDGE + (2 * j + sj0);
      hs[((size_t)(b * SLEN + srow)) * HID + h * HD + d0] = f2bf(acc0[cell] * w);
    }
    {
      int srow = OFF + (2 * i + si1) * EDGE + (2 * j + sj1);
      hs[((size_t)(b * SLEN + srow)) * HID + h * HD + d1] = f2bf(acc1[cell] * w);
    }
  }
}

// ---------------- Kernel E: single-barrier counted-vmcnt bf16 MFMA GEMM ----------------
// C[m,e] = resid[m,e] + silu( sum_d A[m,d] * W[e,d] ),  M=2048, N=K=4096.
// BM=128, BN=256, BK=64; 256 blocks (1/CU), 512 threads (8 waves, 2Mx4N).
// Triple-buffered LDS, depth-2 prefetch, ONE vmcnt(6)+barrier per K-tile.
__global__ __launch_bounds__(512, 2) void k_gemm(const unsigned short* __restrict__ A,
                                                 const unsigned short* __restrict__ Bm,
                                                 const float* __restrict__ resid,
                                                 float* __restrict__ out) {
  __shared__ unsigned short lA[3][128 * 64];   // 48 KB
  __shared__ unsigned short lB[3][256 * 64];   // 96 KB

  int bid0 = blockIdx.x;
  int swz = (bid0 & 7) * 32 + (bid0 >> 3);     // XCD-contiguous (256 % 8 == 0)
  int bm0 = (swz & 15) << 7;
  int bn0 = (swz >> 4) << 8;                   // each XCD: 512-col B slice = 4 MB L2
  int t = threadIdx.x;
  int ln = t & 63, wv = t >> 6;
  int wr = wv >> 2, wc = wv & 3;               // 2 x 4 wave grid, 64x64 C per wave

  int aOff[4][2], bOff[4][2];
#pragma unroll
  for (int q = 0; q < 4; ++q)
#pragma unroll
    for (int ks = 0; ks < 2; ++ks) {
      int ga = ks * 4 + (ln >> 4);
      int ra = wr * 64 + q * 16 + (ln & 15);
      aOff[q][ks] = ra * 64 + ((ga ^ (ra & 7)) * 8);
      int rb = wc * 64 + q * 16 + (ln & 15);
      bOff[q][ks] = rb * 64 + ((ga ^ (rb & 7)) * 8);
    }

  const unsigned short* aS0; const unsigned short* aS1;
  unsigned short *aD0, *aD1;
  {
    int G = t, r = G >> 3, g = G & 7;
    aS0 = A + (size_t)(bm0 + r) * HID + ((g ^ (r & 7)) * 8);
    aD0 = &lA[0][0] + G * 8;
    G = t + 512; r = G >> 3; g = G & 7;
    aS1 = A + (size_t)(bm0 + r) * HID + ((g ^ (r & 7)) * 8);
    aD1 = &lA[0][0] + G * 8;
  }
  const unsigned short *bS0, *bS1, *bS2, *bS3;
  unsigned short *bD0, *bD1, *bD2, *bD3;
  {
    int G = t, r = G >> 3, g = G & 7;
    bS0 = Bm + (size_t)(bn0 + r) * HID + ((g ^ (r & 7)) * 8);
    bD0 = &lB[0][0] + G * 8;
    G = t + 512; r = G >> 3; g = G & 7;
    bS1 = Bm + (size_t)(bn0 + r) * HID + ((g ^ (r & 7)) * 8);
    bD1 = &lB[0][0] + G * 8;
    G = t + 1024; r = G >> 3; g = G & 7;
    bS2 = Bm + (size_t)(bn0 + r) * HID + ((g ^ (r & 7)) * 8);
    bD2 = &lB[0][0] + G * 8;
    G = t + 1536; r = G >> 3; g = G & 7;
    bS3 = Bm + (size_t)(bn0 + r) * HID + ((g ^ (r & 7)) * 8);
    bD3 = &lB[0][0] + G * 8;
  }

#define STAGE_ALL(kt_, nb_)                                \
  load_lds16(aS0 + (kt_) * 64, aD0 + (nb_) * 8192);        \
  load_lds16(aS1 + (kt_) * 64, aD1 + (nb_) * 8192);        \
  load_lds16(bS0 + (kt_) * 64, bD0 + (nb_) * 16384);       \
  load_lds16(bS1 + (kt_) * 64, bD1 + (nb_) * 16384);       \
  load_lds16(bS2 + (kt_) * 64, bD2 + (nb_) * 16384);       \
  load_lds16(bS3 + (kt_) * 64, bD3 + (nb_) * 16384);

  f32x4 acc[4][4];
#pragma unroll
  for (int mi = 0; mi < 4; ++mi)
#pragma unroll
    for (int ni = 0; ni < 4; ++ni) acc[mi][ni] = (f32x4){0.f, 0.f, 0.f, 0.f};

  STAGE_ALL(0, 0);
  STAGE_ALL(1, 1);

  int cur = 0;
  for (int kt = 0; kt < 64; ++kt) {
    if (kt < 63) {
      asm volatile("s_waitcnt vmcnt(6)" ::: "memory");
    } else {
      asm volatile("s_waitcnt vmcnt(0)" ::: "memory");
    }
    __builtin_amdgcn_s_barrier();
    __builtin_amdgcn_sched_barrier(0);

    const unsigned short* Ab = &lA[0][0] + cur * 8192;
    const unsigned short* Bb = &lB[0][0] + cur * 16384;

    bf16x8 aF[4][2], bF[4][2];
#pragma unroll
    for (int q = 0; q < 4; ++q) {
      aF[q][0] = *(const bf16x8*)(Ab + aOff[q][0]);
      aF[q][1] = *(const bf16x8*)(Ab + aOff[q][1]);
      bF[q][0] = *(const bf16x8*)(Bb + bOff[q][0]);
      bF[q][1] = *(const bf16x8*)(Bb + bOff[q][1]);
    }

    int nb = cur + 2; if (nb >= 3) nb -= 3;
    if (kt < 62) { STAGE_ALL(kt + 2, nb); }

    __builtin_amdgcn_s_setprio(1);
#pragma unroll
    for (int ni = 0; ni < 4; ++ni)
#pragma unroll
      for (int mi = 0; mi < 4; ++mi) {
        acc[mi][ni] = __builtin_amdgcn_mfma_f32_16x16x32_bf16(aF[mi][0], bF[ni][0],
                                                              acc[mi][ni], 0, 0, 0);
        acc[mi][ni] = __builtin_amdgcn_mfma_f32_16x16x32_bf16(aF[mi][1], bF[ni][1],
                                                              acc[mi][ni], 0, 0, 0);
      }
    __builtin_amdgcn_s_setprio(0);

    cur = cur + 1; if (cur >= 3) cur = 0;
  }
#undef STAGE_ALL

#pragma unroll
  for (int mi = 0; mi < 4; ++mi) {
#pragma unroll
    for (int ni = 0; ni < 4; ++ni) {
      int m = bm0 + wr * 64 + mi * 16 + (ln >> 4) * 4;
      int n = bn0 + wc * 64 + ni * 16 + (ln & 15);
#pragma unroll
      for (int r = 0; r < 4; ++r) {
        float x = acc[mi][ni][r];
        float s = x / (1.f + __expf(-x));
        size_t o = (size_t)(m + r) * HID + n;
        out[o] = resid[o] + s;
      }
    }
  }
}

extern "C" void kernel_launch(void* const* d_in, const int* in_sizes, int n_in,
                              void* d_out, int out_size, void* d_ws, size_t ws_size,
                              hipStream_t stream) {
  const float* hid = (const float*)d_in[0];
  const float* Win = (const float*)d_in[1];
  const float* Wup = (const float*)d_in[2];
  float* out = (float*)d_out;
  char* ws = (char*)d_ws;

  unsigned short* Wb  = (unsigned short*)ws;                 // 33,554,432 B
  unsigned short* Phi = (unsigned short*)(ws + 33554432);    // 16,777,216 B
  float* part = (float*)(ws + 50331648);                     //  1,032,192 B
  float* params = (float*)(ws + 52396032);                   //      1,024 B
  unsigned short* Plo = (unsigned short*)d_out;  // lo plane lives in d_out until k_gemm

  k_cvt<<<16384, 256, 0, stream>>>(Win, Wb, HID * HID / 4);
  k_pack<<<NB * SLEN * HID / 4 / 256, 256, 0, stream>>>(hid, Phi, Plo);
  k_scores<<<448, 512, 0, stream>>>(Phi, Plo, part);
  k_head<<<NB * NH, 256, 0, stream>>>(part, params);
  k_img<<<NB * NH * 4, 256, 0, stream>>>(hid, Wup, params, Phi);
  k_gemm<<<256, 512, 0, stream>>>(Phi, Wb, hid, out);
}